// Round 6
// baseline (709.349 us; speedup 1.0000x reference)
//
#include <hip/hip_runtime.h>
#include <hip/hip_fp16.h>

#define N_NODES 50000
#define N_EDGES 800000
#define DIM 128
#define NUM_GRAPHS 128

// ================= degree / dinv precompute =================

__global__ __launch_bounds__(256) void k_init(float* deg, int* counts, int n) {
    int i = blockIdx.x * 256 + threadIdx.x;
    if (i < n) { deg[i] = 1.0f; counts[i] = 0; }  // self-loop weight, hist=0
}

// fused: deg += attr  and  counts += 1  per in-edge
__global__ __launch_bounds__(256) void k_deg_hist(const int* __restrict__ dst,
                                                  const float* __restrict__ attr,
                                                  float* deg, int* counts, int E) {
    int e = blockIdx.x * 256 + threadIdx.x;
    if (e < E) {
        int d = dst[e];
        atomicAdd(&deg[d], attr[e]);
        atomicAdd(&counts[d], 1);
    }
}

__global__ __launch_bounds__(256) void k_dinv(float* deg, int n) {
    int i = blockIdx.x * 256 + threadIdx.x;
    if (i < n) {
        float d0 = deg[i];
        deg[i] = d0 > 0.f ? rsqrtf(fmaxf(d0, 1e-12f)) : 0.f;
    }
}

// ================= CSR build (sort edges by dst, on device, every call) ====

__global__ __launch_bounds__(256) void k_zero_int(int* p, int n) {
    int i = blockIdx.x * 256 + threadIdx.x;
    if (i < n) p[i] = 0;
}

// 3-kernel exclusive scan over counts[n] -> offs[n]
__global__ __launch_bounds__(256) void k_scan1(const int* __restrict__ counts,
                                               int* __restrict__ offs,
                                               int* __restrict__ partials, int n) {
    __shared__ int tmp[256];
    int t = threadIdx.x;
    int gid = blockIdx.x * 256 + t;
    int v = gid < n ? counts[gid] : 0;
    tmp[t] = v;
    __syncthreads();
    for (int off = 1; off < 256; off <<= 1) {
        int add = (t >= off) ? tmp[t - off] : 0;
        __syncthreads();
        tmp[t] += add;
        __syncthreads();
    }
    if (gid < n) offs[gid] = tmp[t] - v;  // exclusive within block
    if (t == 255) partials[blockIdx.x] = tmp[255];
}

__global__ __launch_bounds__(256) void k_scan2(int* partials, int nb) {  // nb <= 256
    __shared__ int tmp[256];
    int t = threadIdx.x;
    int v = t < nb ? partials[t] : 0;
    tmp[t] = v;
    __syncthreads();
    for (int off = 1; off < 256; off <<= 1) {
        int add = (t >= off) ? tmp[t - off] : 0;
        __syncthreads();
        tmp[t] += add;
        __syncthreads();
    }
    if (t < nb) partials[t] = tmp[t] - v;  // exclusive
}

__global__ __launch_bounds__(256) void k_scan3(int* __restrict__ offs,
                                               const int* __restrict__ partials, int n) {
    int gid = blockIdx.x * 256 + threadIdx.x;
    if (gid < n) offs[gid] += partials[blockIdx.x];
}

// scatter edges to dst-sorted array; packs (src:u16 | norm:fp16) per edge
__global__ __launch_bounds__(256) void k_scatter_edges(const int* __restrict__ src,
                                                       const int* __restrict__ dst,
                                                       const float* __restrict__ attr,
                                                       const float* __restrict__ dinv,
                                                       const int* __restrict__ offs,
                                                       int* cur,
                                                       unsigned int* __restrict__ epack,
                                                       int E) {
    int e = blockIdx.x * 256 + threadIdx.x;
    if (e >= E) return;
    int s = src[e];
    int d = dst[e];
    int p = offs[d] + atomicAdd(&cur[d], 1);
    __half hn = __float2half_rn(dinv[s] * attr[e] * dinv[d]);
    unsigned short us = *reinterpret_cast<unsigned short*>(&hn);
    epack[p] = ((unsigned int)us << 16) | (unsigned int)s;
}

// ========= GEMM (N x 128) @ (128 x 128), fp32 math, fp16 output table =======

__global__ __launch_bounds__(256) void k_gemm16(const float* __restrict__ A,
                                                const float* __restrict__ W,
                                                __half* __restrict__ H, int n) {
    __shared__ float4 sW[128 * 32];  // 64 KB
    int tid = threadIdx.x;
    const float4* W4 = (const float4*)W;
#pragma unroll
    for (int i = 0; i < 16; i++) sW[tid + i * 256] = W4[tid + i * 256];
    __syncthreads();

    int tx = tid & 31;   // cols 4*tx .. 4*tx+3
    int ty = tid >> 5;   // 8 row groups of 4 rows
    int row0 = blockIdx.x * 32 + ty * 4;

    const float4* Ar[4];
#pragma unroll
    for (int r = 0; r < 4; r++) {
        int rr = row0 + r;
        if (rr >= n) rr = n - 1;
        Ar[r] = (const float4*)(A + (size_t)rr * DIM);
    }

    float4 acc[4];
#pragma unroll
    for (int r = 0; r < 4; r++) acc[r] = make_float4(0.f, 0.f, 0.f, 0.f);

    for (int k4 = 0; k4 < 32; k4++) {
        float4 w0 = sW[(4 * k4 + 0) * 32 + tx];
        float4 w1 = sW[(4 * k4 + 1) * 32 + tx];
        float4 w2 = sW[(4 * k4 + 2) * 32 + tx];
        float4 w3 = sW[(4 * k4 + 3) * 32 + tx];
#pragma unroll
        for (int r = 0; r < 4; r++) {
            float4 a = Ar[r][k4];
            acc[r].x += a.x * w0.x + a.y * w1.x + a.z * w2.x + a.w * w3.x;
            acc[r].y += a.x * w0.y + a.y * w1.y + a.z * w2.y + a.w * w3.y;
            acc[r].z += a.x * w0.z + a.y * w1.z + a.z * w2.z + a.w * w3.z;
            acc[r].w += a.x * w0.w + a.y * w1.w + a.z * w2.w + a.w * w3.w;
        }
    }

#pragma unroll
    for (int r = 0; r < 4; r++) {
        int rr = row0 + r;
        if (rr < n) {
            __half2 h01 = __floats2half2_rn(acc[r].x, acc[r].y);
            __half2 h23 = __floats2half2_rn(acc[r].z, acc[r].w);
            uint2 pk;
            pk.x = *reinterpret_cast<unsigned int*>(&h01);
            pk.y = *reinterpret_cast<unsigned int*>(&h23);
            ((uint2*)(H + (size_t)rr * DIM))[tx] = pk;  // 8B/lane, 256B/row
        }
    }
}

// ===== CSR gather, quarter-wave rows ========================================
// One node per 16 lanes: lane cl in [0,16) holds 16 B (8 fp16 cols) of the
// 256 B row -> ONE dwordx4 instruction gathers 4 edges' rows (4 nodes/wave).
// 4x fewer row-load instructions than half-wave layout; edge meta fetched 8
// at a time with a single dword instruction and distributed via __shfl.

__device__ __forceinline__ float2 unpack_h2(unsigned int u) {
    __half2 h = *reinterpret_cast<__half2*>(&u);
    return __half22float2(h);
}

template <bool POOL>
__global__ __launch_bounds__(256) void k_gather(const __half* __restrict__ H,
                                                const int* __restrict__ offs,
                                                const unsigned int* __restrict__ epack,
                                                const float* __restrict__ dinv,
                                                const float* __restrict__ bias,
                                                const int* __restrict__ batch,
                                                float* __restrict__ OUT,
                                                float* gsum, float* cnt, int n) {
    int tid = blockIdx.x * 256 + threadIdx.x;
    int i = tid >> 4;          // node (16 threads per node)
    int lane = threadIdx.x & 63;  // lane in wave
    int cl = lane & 15;        // column-lane within quarter: 16 B each
    if (i >= n) return;
    const uint4* H16 = (const uint4*)H;  // one row = 16 uint4 (16 B/lane)

    float di = dinv[i];
    float sw = di * di;
    uint4 selfraw = H16[(size_t)i * 16 + cl];
    float acc[8];
    {
        float2 f0 = unpack_h2(selfraw.x);
        float2 f1 = unpack_h2(selfraw.y);
        float2 f2 = unpack_h2(selfraw.z);
        float2 f3 = unpack_h2(selfraw.w);
        acc[0] = sw * f0.x; acc[1] = sw * f0.y;
        acc[2] = sw * f1.x; acc[3] = sw * f1.y;
        acc[4] = sw * f2.x; acc[5] = sw * f2.y;
        acc[6] = sw * f3.x; acc[7] = sw * f3.y;
    }

    int j0 = offs[i];                                  // uniform per quarter
    int end = (i == n - 1) ? N_EDGES : offs[i + 1];

    for (int j = j0; !__all(j >= end); j += 8) {
        // one dword instruction fetches 8 metas per quarter (lanes 0-7 of the
        // quarter distinct, 8-15 duplicates); clamp keeps it in-bounds.
        int jm = j + (cl & 7);
        int jc = jm < (N_EDGES - 1) ? jm : (N_EDGES - 1);
        if (jc < 0) jc = 0;
        unsigned int pe = epack[jc];

        int s[8];
        float w[8];
#pragma unroll
        for (int k = 0; k < 8; k++) {
            unsigned int pk = __shfl(pe, (lane & 48) | k);  // quarter's edge k
            s[k] = (int)(pk & 0xffffu);
            __half_raw hr;
            hr.x = (unsigned short)(pk >> 16);
            float wv = __half2float(__half(hr));
            w[k] = ((j + k) < end) ? wv : 0.f;
        }
        uint4 v[8];
#pragma unroll
        for (int k = 0; k < 8; k++) v[k] = H16[(size_t)s[k] * 16 + cl];
#pragma unroll
        for (int k = 0; k < 8; k++) {
            float2 f0 = unpack_h2(v[k].x);
            float2 f1 = unpack_h2(v[k].y);
            float2 f2 = unpack_h2(v[k].z);
            float2 f3 = unpack_h2(v[k].w);
            acc[0] += w[k] * f0.x; acc[1] += w[k] * f0.y;
            acc[2] += w[k] * f1.x; acc[3] += w[k] * f1.y;
            acc[4] += w[k] * f2.x; acc[5] += w[k] * f2.y;
            acc[6] += w[k] * f3.x; acc[7] += w[k] * f3.y;
        }
    }

    // bias + relu (8 cols per lane: cl*8 .. cl*8+7)
    const float4* B4 = (const float4*)bias;
    float4 bb0 = B4[cl * 2 + 0];
    float4 bb1 = B4[cl * 2 + 1];
    acc[0] = fmaxf(acc[0] + bb0.x, 0.f);
    acc[1] = fmaxf(acc[1] + bb0.y, 0.f);
    acc[2] = fmaxf(acc[2] + bb0.z, 0.f);
    acc[3] = fmaxf(acc[3] + bb0.w, 0.f);
    acc[4] = fmaxf(acc[4] + bb1.x, 0.f);
    acc[5] = fmaxf(acc[5] + bb1.y, 0.f);
    acc[6] = fmaxf(acc[6] + bb1.z, 0.f);
    acc[7] = fmaxf(acc[7] + bb1.w, 0.f);

    if (POOL) {
        int g = batch[i];
        float* o = gsum + (size_t)g * DIM + cl * 8;
#pragma unroll
        for (int c = 0; c < 8; c++) atomicAdd(o + c, acc[c]);
        if (cl == 0) atomicAdd(&cnt[g], 1.0f);
    } else {
        float4* O4 = (float4*)(OUT + (size_t)i * DIM + cl * 8);
        O4[0] = make_float4(acc[0], acc[1], acc[2], acc[3]);
        O4[1] = make_float4(acc[4], acc[5], acc[6], acc[7]);
    }
}

// ================= pooling scratch zero + classifier =================

__global__ __launch_bounds__(256) void k_zero(float* p, int n) {
    int i = blockIdx.x * 256 + threadIdx.x;
    if (i < n) p[i] = 0.f;
}

__global__ __launch_bounds__(128) void k_classifier(const float* __restrict__ gsum,
                                                    const float* __restrict__ cnt,
                                                    const float* __restrict__ Wc1,
                                                    const float* __restrict__ bc1,
                                                    const float* __restrict__ Wc2,
                                                    const float* __restrict__ bc2,
                                                    float* __restrict__ out) {
    int g = blockIdx.x;
    int t = threadIdx.x;  // 128
    __shared__ float gv[128];
    __shared__ float hid[128];
    float inv = 1.0f / fmaxf(cnt[g], 1.0f);
    gv[t] = gsum[(size_t)g * DIM + t] * inv;
    __syncthreads();
    float acc = bc1[t];
    for (int k = 0; k < 128; k++) acc += gv[k] * Wc1[k * 128 + t];
    hid[t] = fmaxf(acc, 0.f);
    __syncthreads();
    if (t < 4) {
        float o = bc2[t];
        for (int k = 0; k < 128; k++) o += hid[k] * Wc2[k * 4 + t];
        out[g * 4 + t] = o;
    }
}

// ================= launch =================

extern "C" void kernel_launch(void* const* d_in, const int* in_sizes, int n_in,
                              void* d_out, int out_size, void* d_ws, size_t ws_size,
                              hipStream_t stream) {
    const float* x     = (const float*)d_in[0];
    const int*   ei    = (const int*)d_in[1];  // [2, E]: src then dst
    const float* attr  = (const float*)d_in[2];
    // d_in[3] edge_weight: unused by reference
    const int*   batch = (const int*)d_in[4];
    const float* W0  = (const float*)d_in[5];
    const float* b0  = (const float*)d_in[6];
    const float* W1  = (const float*)d_in[7];
    const float* b1  = (const float*)d_in[8];
    const float* Wc1 = (const float*)d_in[9];
    const float* bc1 = (const float*)d_in[10];
    const float* Wc2 = (const float*)d_in[11];
    const float* bc2 = (const float*)d_in[12];
    float* out = (float*)d_out;

    char* ws = (char*)d_ws;
    __half*       bufH16   = (__half*)(ws + 0);            // 12,800,000
    float*        bufA     = (float*)(ws + 12800000);      // 25,600,000
    unsigned int* epack    = (unsigned int*)(ws + 38400000);  // 3,200,000 (+pad)
    float*        dinv     = (float*)(ws + 41600128);      //    200,000
    int*          offs     = (int*)(ws + 41800128);        //    200,064
    int*          counts   = (int*)(ws + 42000192);        //    200,000 (also cursor)
    int*          partials = (int*)(ws + 42200192);        //      1,024
    float*        gsum     = (float*)(ws + 42201216);      //     65,536
    float*        cnt      = (float*)(ws + 42266752);      //        512

    const int* src = ei;
    const int* dst = ei + N_EDGES;

    const int NB_N = (N_NODES + 255) / 256;   // 196
    const int NB_E = (N_EDGES + 255) / 256;   // 3125

    // deg/hist fused precompute
    k_init<<<NB_N, 256, 0, stream>>>(dinv, counts, N_NODES);
    k_deg_hist<<<NB_E, 256, 0, stream>>>(dst, attr, dinv, counts, N_EDGES);
    k_dinv<<<NB_N, 256, 0, stream>>>(dinv, N_NODES);

    // CSR: exclusive scan of counts -> offs; scatter packed (src|norm) by dst
    k_scan1<<<NB_N, 256, 0, stream>>>(counts, offs, partials, N_NODES);
    k_scan2<<<1, 256, 0, stream>>>(partials, NB_N);
    k_scan3<<<NB_N, 256, 0, stream>>>(offs, partials, N_NODES);
    k_zero_int<<<NB_N, 256, 0, stream>>>(counts, N_NODES);  // reuse as cursor
    k_scatter_edges<<<NB_E, 256, 0, stream>>>(src, dst, attr, dinv, offs, counts,
                                              epack, N_EDGES);

    // zero pool accumulators (ws is poisoned each call)
    k_zero<<<(NUM_GRAPHS * DIM + NUM_GRAPHS + 255) / 256, 256, 0, stream>>>(
        gsum, NUM_GRAPHS * DIM + NUM_GRAPHS);

    const int NB_G = (N_NODES * 16 + 255) / 256;  // 3125 (16 threads per node)

    // layer 1: gemm(fp16 table) + gather(bias+relu fused)
    k_gemm16<<<(N_NODES + 31) / 32, 256, 0, stream>>>(x, W0, bufH16, N_NODES);
    k_gather<false><<<NB_G, 256, 0, stream>>>(bufH16, offs, epack, dinv, b0,
                                              batch, bufA, gsum, cnt, N_NODES);

    // layer 2: gemm(fp16 table) + gather(bias+relu+mean-pool fused)
    k_gemm16<<<(N_NODES + 31) / 32, 256, 0, stream>>>(bufA, W1, bufH16, N_NODES);
    k_gather<true><<<NB_G, 256, 0, stream>>>(bufH16, offs, epack, dinv, b1,
                                             batch, nullptr, gsum, cnt, N_NODES);

    // classifier
    k_classifier<<<NUM_GRAPHS, 128, 0, stream>>>(gsum, cnt, Wc1, bc1, Wc2, bc2, out);
}

// Round 7
// 387.466 us; speedup vs baseline: 1.8307x; 1.8307x over previous
//
#include <hip/hip_runtime.h>
#include <hip/hip_fp16.h>

#define N_NODES 50000
#define N_EDGES 800000
#define DIM 128
#define NUM_GRAPHS 128

// ================= degree / dinv precompute =================

__global__ __launch_bounds__(256) void k_init(float* deg, int* counts, int n) {
    int i = blockIdx.x * 256 + threadIdx.x;
    if (i < n) { deg[i] = 1.0f; counts[i] = 0; }  // self-loop weight, hist=0
}

// fused: deg += attr  and  counts += 1  per in-edge
__global__ __launch_bounds__(256) void k_deg_hist(const int* __restrict__ dst,
                                                  const float* __restrict__ attr,
                                                  float* deg, int* counts, int E) {
    int e = blockIdx.x * 256 + threadIdx.x;
    if (e < E) {
        int d = dst[e];
        atomicAdd(&deg[d], attr[e]);
        atomicAdd(&counts[d], 1);
    }
}

__global__ __launch_bounds__(256) void k_dinv(float* deg, int n) {
    int i = blockIdx.x * 256 + threadIdx.x;
    if (i < n) {
        float d0 = deg[i];
        deg[i] = d0 > 0.f ? rsqrtf(fmaxf(d0, 1e-12f)) : 0.f;
    }
}

// ================= CSR build (sort edges by dst, on device, every call) ====

__global__ __launch_bounds__(256) void k_zero_int(int* p, int n) {
    int i = blockIdx.x * 256 + threadIdx.x;
    if (i < n) p[i] = 0;
}

// 3-kernel exclusive scan over counts[n] -> offs[n]
__global__ __launch_bounds__(256) void k_scan1(const int* __restrict__ counts,
                                               int* __restrict__ offs,
                                               int* __restrict__ partials, int n) {
    __shared__ int tmp[256];
    int t = threadIdx.x;
    int gid = blockIdx.x * 256 + t;
    int v = gid < n ? counts[gid] : 0;
    tmp[t] = v;
    __syncthreads();
    for (int off = 1; off < 256; off <<= 1) {
        int add = (t >= off) ? tmp[t - off] : 0;
        __syncthreads();
        tmp[t] += add;
        __syncthreads();
    }
    if (gid < n) offs[gid] = tmp[t] - v;  // exclusive within block
    if (t == 255) partials[blockIdx.x] = tmp[255];
}

__global__ __launch_bounds__(256) void k_scan2(int* partials, int nb) {  // nb <= 256
    __shared__ int tmp[256];
    int t = threadIdx.x;
    int v = t < nb ? partials[t] : 0;
    tmp[t] = v;
    __syncthreads();
    for (int off = 1; off < 256; off <<= 1) {
        int add = (t >= off) ? tmp[t - off] : 0;
        __syncthreads();
        tmp[t] += add;
        __syncthreads();
    }
    if (t < nb) partials[t] = tmp[t] - v;  // exclusive
}

__global__ __launch_bounds__(256) void k_scan3(int* __restrict__ offs,
                                               const int* __restrict__ partials, int n) {
    int gid = blockIdx.x * 256 + threadIdx.x;
    if (gid < n) offs[gid] += partials[blockIdx.x];
}

// scatter edges to dst-sorted array; packs (src:u16 | norm:fp16) per edge
__global__ __launch_bounds__(256) void k_scatter_edges(const int* __restrict__ src,
                                                       const int* __restrict__ dst,
                                                       const float* __restrict__ attr,
                                                       const float* __restrict__ dinv,
                                                       const int* __restrict__ offs,
                                                       int* cur,
                                                       unsigned int* __restrict__ epack,
                                                       int E) {
    int e = blockIdx.x * 256 + threadIdx.x;
    if (e >= E) return;
    int s = src[e];
    int d = dst[e];
    int p = offs[d] + atomicAdd(&cur[d], 1);
    __half hn = __float2half_rn(dinv[s] * attr[e] * dinv[d]);
    unsigned short us = *reinterpret_cast<unsigned short*>(&hn);
    epack[p] = ((unsigned int)us << 16) | (unsigned int)s;
}

// ========= GEMM (N x 128) @ (128 x 128), fp32 math, fp16 output table =======

__global__ __launch_bounds__(256) void k_gemm16(const float* __restrict__ A,
                                                const float* __restrict__ W,
                                                __half* __restrict__ H, int n) {
    __shared__ float4 sW[128 * 32];  // 64 KB
    int tid = threadIdx.x;
    const float4* W4 = (const float4*)W;
#pragma unroll
    for (int i = 0; i < 16; i++) sW[tid + i * 256] = W4[tid + i * 256];
    __syncthreads();

    int tx = tid & 31;   // cols 4*tx .. 4*tx+3
    int ty = tid >> 5;   // 8 row groups of 4 rows
    int row0 = blockIdx.x * 32 + ty * 4;

    const float4* Ar[4];
#pragma unroll
    for (int r = 0; r < 4; r++) {
        int rr = row0 + r;
        if (rr >= n) rr = n - 1;
        Ar[r] = (const float4*)(A + (size_t)rr * DIM);
    }

    float4 acc[4];
#pragma unroll
    for (int r = 0; r < 4; r++) acc[r] = make_float4(0.f, 0.f, 0.f, 0.f);

    for (int k4 = 0; k4 < 32; k4++) {
        float4 w0 = sW[(4 * k4 + 0) * 32 + tx];
        float4 w1 = sW[(4 * k4 + 1) * 32 + tx];
        float4 w2 = sW[(4 * k4 + 2) * 32 + tx];
        float4 w3 = sW[(4 * k4 + 3) * 32 + tx];
#pragma unroll
        for (int r = 0; r < 4; r++) {
            float4 a = Ar[r][k4];
            acc[r].x += a.x * w0.x + a.y * w1.x + a.z * w2.x + a.w * w3.x;
            acc[r].y += a.x * w0.y + a.y * w1.y + a.z * w2.y + a.w * w3.y;
            acc[r].z += a.x * w0.z + a.y * w1.z + a.z * w2.z + a.w * w3.z;
            acc[r].w += a.x * w0.w + a.y * w1.w + a.z * w2.w + a.w * w3.w;
        }
    }

#pragma unroll
    for (int r = 0; r < 4; r++) {
        int rr = row0 + r;
        if (rr < n) {
            __half2 h01 = __floats2half2_rn(acc[r].x, acc[r].y);
            __half2 h23 = __floats2half2_rn(acc[r].z, acc[r].w);
            uint2 pk;
            pk.x = *reinterpret_cast<unsigned int*>(&h01);
            pk.y = *reinterpret_cast<unsigned int*>(&h23);
            ((uint2*)(H + (size_t)rr * DIM))[tx] = pk;  // 8B/lane, 256B/row
        }
    }
}

// ===== CSR gather: out[d] = relu(bias + dinv[d]^2 h[d] + sum nrm*h[src]) =====
// fp16 table (256 B rows), fp32 accumulation. 32 lanes/node, 8-deep predicated
// pipeline. POOL: block-level segmented reduction over the SORTED batch array
// (one graph per 8-node block in ~98% of blocks) -> ~129 atomics/block instead
// of 1024 (global fp32 atomics issue at ~1/8cyc/CU; 25.6M of them was the
// entire 330 us of the old pool gather).

__device__ __forceinline__ float2 unpack_h2(unsigned int u) {
    __half2 h = *reinterpret_cast<__half2*>(&u);
    return __half22float2(h);
}

template <bool POOL>
__global__ __launch_bounds__(256) void k_gather(const __half* __restrict__ H,
                                                const int* __restrict__ offs,
                                                const unsigned int* __restrict__ epack,
                                                const float* __restrict__ dinv,
                                                const float* __restrict__ bias,
                                                const int* __restrict__ batch,
                                                float* __restrict__ OUT,
                                                float* gsum, float* cnt, int n) {
    __shared__ float lpool[8 * 128];  // 4 KB (POOL reduction)
    __shared__ int sg[8];

    int idx = blockIdx.x * 256 + threadIdx.x;
    int i = idx >> 5;          // node; grid is exact (6250*8 == 50000)
    int lane = idx & 31;
    int w = threadIdx.x >> 5;  // node slot within block
    const uint2* H8 = (const uint2*)H;  // one row = 32 uint2 (8B/lane)

    float di = dinv[i];
    float sw = di * di;
    uint2 selfraw = H8[(size_t)i * 32 + lane];
    float2 s01 = unpack_h2(selfraw.x);
    float2 s23 = unpack_h2(selfraw.y);
    float4 acc = make_float4(sw * s01.x, sw * s01.y, sw * s23.x, sw * s23.y);

    int j0 = offs[i];
    int end = (i == n - 1) ? N_EDGES : offs[i + 1];

    for (int j = j0; j < end; j += 8) {
        int s[8];
        float wt[8];
#pragma unroll
        for (int k = 0; k < 8; k++) {
            int jj = j + k;
            bool valid = jj < end;
            int jc = valid ? jj : (end - 1);
            unsigned int pe = epack[jc];
            s[k] = (int)(pe & 0xffffu);
            __half_raw hr;
            hr.x = (unsigned short)(pe >> 16);
            float wv = __half2float(__half(hr));
            wt[k] = valid ? wv : 0.f;
        }
        uint2 v[8];
#pragma unroll
        for (int k = 0; k < 8; k++) v[k] = H8[(size_t)s[k] * 32 + lane];
#pragma unroll
        for (int k = 0; k < 8; k++) {
            float2 f01 = unpack_h2(v[k].x);
            float2 f23 = unpack_h2(v[k].y);
            acc.x += wt[k] * f01.x;
            acc.y += wt[k] * f01.y;
            acc.z += wt[k] * f23.x;
            acc.w += wt[k] * f23.y;
        }
    }

    float4 bb = ((const float4*)bias)[lane];
    acc.x = fmaxf(acc.x + bb.x, 0.f);
    acc.y = fmaxf(acc.y + bb.y, 0.f);
    acc.z = fmaxf(acc.z + bb.z, 0.f);
    acc.w = fmaxf(acc.w + bb.w, 0.f);

    if (POOL) {
        int g = batch[i];
        if (lane == 0) sg[w] = g;
        __syncthreads();
        bool uniform = true;
#pragma unroll
        for (int k = 0; k < 8; k++) uniform = uniform && (sg[k] == sg[0]);
        if (uniform) {
            // block-wide reduction: 8 nodes -> 1 partial, 129 atomics/block
            ((float4*)(lpool + w * 128))[lane] = acc;
            __syncthreads();
            int t = threadIdx.x;
            if (t < 128) {
                float s = 0.f;
#pragma unroll
                for (int k = 0; k < 8; k++) s += lpool[k * 128 + t];
                atomicAdd(&gsum[sg[0] * DIM + t], s);
            }
            if (t == 0) atomicAdd(&cnt[sg[0]], 8.0f);
        } else {
            // graph boundary inside block (~2% of blocks): per-node atomics
            float* o = gsum + (size_t)g * DIM + lane * 4;
            atomicAdd(o + 0, acc.x);
            atomicAdd(o + 1, acc.y);
            atomicAdd(o + 2, acc.z);
            atomicAdd(o + 3, acc.w);
            if (lane == 0) atomicAdd(&cnt[g], 1.0f);
        }
    } else {
        ((float4*)OUT)[(size_t)i * 32 + lane] = acc;
    }
}

// ================= pooling scratch zero + classifier =================

__global__ __launch_bounds__(256) void k_zero(float* p, int n) {
    int i = blockIdx.x * 256 + threadIdx.x;
    if (i < n) p[i] = 0.f;
}

__global__ __launch_bounds__(128) void k_classifier(const float* __restrict__ gsum,
                                                    const float* __restrict__ cnt,
                                                    const float* __restrict__ Wc1,
                                                    const float* __restrict__ bc1,
                                                    const float* __restrict__ Wc2,
                                                    const float* __restrict__ bc2,
                                                    float* __restrict__ out) {
    int g = blockIdx.x;
    int t = threadIdx.x;  // 128
    __shared__ float gv[128];
    __shared__ float hid[128];
    float inv = 1.0f / fmaxf(cnt[g], 1.0f);
    gv[t] = gsum[(size_t)g * DIM + t] * inv;
    __syncthreads();
    float acc = bc1[t];
    for (int k = 0; k < 128; k++) acc += gv[k] * Wc1[k * 128 + t];
    hid[t] = fmaxf(acc, 0.f);
    __syncthreads();
    if (t < 4) {
        float o = bc2[t];
        for (int k = 0; k < 128; k++) o += hid[k] * Wc2[k * 4 + t];
        out[g * 4 + t] = o;
    }
}

// ================= launch =================

extern "C" void kernel_launch(void* const* d_in, const int* in_sizes, int n_in,
                              void* d_out, int out_size, void* d_ws, size_t ws_size,
                              hipStream_t stream) {
    const float* x     = (const float*)d_in[0];
    const int*   ei    = (const int*)d_in[1];  // [2, E]: src then dst
    const float* attr  = (const float*)d_in[2];
    // d_in[3] edge_weight: unused by reference
    const int*   batch = (const int*)d_in[4];
    const float* W0  = (const float*)d_in[5];
    const float* b0  = (const float*)d_in[6];
    const float* W1  = (const float*)d_in[7];
    const float* b1  = (const float*)d_in[8];
    const float* Wc1 = (const float*)d_in[9];
    const float* bc1 = (const float*)d_in[10];
    const float* Wc2 = (const float*)d_in[11];
    const float* bc2 = (const float*)d_in[12];
    float* out = (float*)d_out;

    char* ws = (char*)d_ws;
    __half*       bufH16   = (__half*)(ws + 0);            // 12,800,000
    float*        bufA     = (float*)(ws + 12800000);      // 25,600,000
    unsigned int* epack    = (unsigned int*)(ws + 38400000);  // 3,200,000
    float*        dinv     = (float*)(ws + 41600128);      //    200,000
    int*          offs     = (int*)(ws + 41800128);        //    200,064
    int*          counts   = (int*)(ws + 42000192);        //    200,000 (also cursor)
    int*          partials = (int*)(ws + 42200192);        //      1,024
    float*        gsum     = (float*)(ws + 42201216);      //     65,536
    float*        cnt      = (float*)(ws + 42266752);      //        512

    const int* src = ei;
    const int* dst = ei + N_EDGES;

    const int NB_N = (N_NODES + 255) / 256;   // 196
    const int NB_E = (N_EDGES + 255) / 256;   // 3125

    // deg/hist fused precompute
    k_init<<<NB_N, 256, 0, stream>>>(dinv, counts, N_NODES);
    k_deg_hist<<<NB_E, 256, 0, stream>>>(dst, attr, dinv, counts, N_EDGES);
    k_dinv<<<NB_N, 256, 0, stream>>>(dinv, N_NODES);

    // CSR: exclusive scan of counts -> offs; scatter packed (src|norm) by dst
    k_scan1<<<NB_N, 256, 0, stream>>>(counts, offs, partials, N_NODES);
    k_scan2<<<1, 256, 0, stream>>>(partials, NB_N);
    k_scan3<<<NB_N, 256, 0, stream>>>(offs, partials, N_NODES);
    k_zero_int<<<NB_N, 256, 0, stream>>>(counts, N_NODES);  // reuse as cursor
    k_scatter_edges<<<NB_E, 256, 0, stream>>>(src, dst, attr, dinv, offs, counts,
                                              epack, N_EDGES);

    // zero pool accumulators (ws is poisoned each call)
    k_zero<<<(NUM_GRAPHS * DIM + NUM_GRAPHS + 255) / 256, 256, 0, stream>>>(
        gsum, NUM_GRAPHS * DIM + NUM_GRAPHS);

    const int NB_G = (N_NODES * 32 + 255) / 256;  // 6250 (exact: 8 nodes/block)

    // layer 1: gemm(fp16 table) + gather(bias+relu fused)
    k_gemm16<<<(N_NODES + 31) / 32, 256, 0, stream>>>(x, W0, bufH16, N_NODES);
    k_gather<false><<<NB_G, 256, 0, stream>>>(bufH16, offs, epack, dinv, b0,
                                              batch, bufA, gsum, cnt, N_NODES);

    // layer 2: gemm(fp16 table) + gather(bias+relu+segmented-mean-pool fused)
    k_gemm16<<<(N_NODES + 31) / 32, 256, 0, stream>>>(bufA, W1, bufH16, N_NODES);
    k_gather<true><<<NB_G, 256, 0, stream>>>(bufH16, offs, epack, dinv, b1,
                                             batch, nullptr, gsum, cnt, N_NODES);

    // classifier
    k_classifier<<<NUM_GRAPHS, 128, 0, stream>>>(gsum, cnt, Wc1, bc1, Wc2, bc2, out);
}

// Round 8
// 319.909 us; speedup vs baseline: 2.2173x; 1.2112x over previous
//
#include <hip/hip_runtime.h>
#include <hip/hip_fp16.h>

#define N_NODES 50000
#define N_EDGES 800000
#define DIM 128
#define NUM_GRAPHS 128

#define ATTR_SCALE 33554432.0f        // 2^25 fixed-point for attr sums
#define ATTR_MASK  ((1ull << 40) - 1)

// ================= init: zero packed (count<<40 | attrsum) =================

__global__ __launch_bounds__(256) void k_zero_u64(unsigned long long* p, int n) {
    int i = blockIdx.x * 256 + threadIdx.x;
    if (i < n) p[i] = 0ull;
}

// ===== one u64 atomic per edge: counts AND attr-sum AND per-dst rank ======
// addend = (1<<40) | round(attr * 2^25). Returned old value's high bits give
// this edge's arrival rank within its dst — used later as the CSR slot, so
// the scatter pass needs no cursor atomic at all.

__global__ __launch_bounds__(256) void k_deg_hist(const int* __restrict__ dst,
                                                  const float* __restrict__ attr,
                                                  unsigned long long* packed,
                                                  unsigned short* __restrict__ rank,
                                                  int E) {
    int e = blockIdx.x * 256 + threadIdx.x;
    if (e >= E) return;
    int d = dst[e];
    unsigned long long add =
        (1ull << 40) | (unsigned long long)(unsigned int)(attr[e] * ATTR_SCALE + 0.5f);
    unsigned long long old = atomicAdd(&packed[d], add);
    rank[e] = (unsigned short)(old >> 40);
}

// ===== scan over counts (fused: unpack deg -> dinv = rsqrt(1+sum attr)) ====

__global__ __launch_bounds__(256) void k_scan1(const unsigned long long* __restrict__ packed,
                                               float* __restrict__ dinv,
                                               int* __restrict__ offs,
                                               int* __restrict__ partials, int n) {
    __shared__ int tmp[256];
    int t = threadIdx.x;
    int gid = blockIdx.x * 256 + t;
    int v = 0;
    if (gid < n) {
        unsigned long long pk = packed[gid];
        v = (int)(pk >> 40);
        float deg = 1.0f + (float)(pk & ATTR_MASK) * (1.0f / ATTR_SCALE);
        dinv[gid] = rsqrtf(deg);  // deg >= 1 always (self-loop)
    }
    tmp[t] = v;
    __syncthreads();
    for (int off = 1; off < 256; off <<= 1) {
        int add = (t >= off) ? tmp[t - off] : 0;
        __syncthreads();
        tmp[t] += add;
        __syncthreads();
    }
    if (gid < n) offs[gid] = tmp[t] - v;  // exclusive within block
    if (t == 255) partials[blockIdx.x] = tmp[255];
}

__global__ __launch_bounds__(256) void k_scan2(int* partials, int nb) {  // nb <= 256
    __shared__ int tmp[256];
    int t = threadIdx.x;
    int v = t < nb ? partials[t] : 0;
    tmp[t] = v;
    __syncthreads();
    for (int off = 1; off < 256; off <<= 1) {
        int add = (t >= off) ? tmp[t - off] : 0;
        __syncthreads();
        tmp[t] += add;
        __syncthreads();
    }
    if (t < nb) partials[t] = tmp[t] - v;  // exclusive
}

__global__ __launch_bounds__(256) void k_scan3(int* __restrict__ offs,
                                               const int* __restrict__ partials, int n) {
    int gid = blockIdx.x * 256 + threadIdx.x;
    if (gid < n) offs[gid] += partials[blockIdx.x];
}

// ===== scatter edges to dst-sorted array — NO atomics (rank precomputed) ===

__global__ __launch_bounds__(256) void k_scatter_edges(const int* __restrict__ src,
                                                       const int* __restrict__ dst,
                                                       const float* __restrict__ attr,
                                                       const float* __restrict__ dinv,
                                                       const int* __restrict__ offs,
                                                       const unsigned short* __restrict__ rank,
                                                       unsigned int* __restrict__ epack,
                                                       int E) {
    int e = blockIdx.x * 256 + threadIdx.x;
    if (e >= E) return;
    int s = src[e];
    int d = dst[e];
    int p = offs[d] + (int)rank[e];
    __half hn = __float2half_rn(dinv[s] * attr[e] * dinv[d]);
    unsigned short us = *reinterpret_cast<unsigned short*>(&hn);
    epack[p] = ((unsigned int)us << 16) | (unsigned int)s;
}

// ========= GEMM (N x 128) @ (128 x 128), fp32 math, fp16 output table =======

__global__ __launch_bounds__(256) void k_gemm16(const float* __restrict__ A,
                                                const float* __restrict__ W,
                                                __half* __restrict__ H, int n) {
    __shared__ float4 sW[128 * 32];  // 64 KB
    int tid = threadIdx.x;
    const float4* W4 = (const float4*)W;
#pragma unroll
    for (int i = 0; i < 16; i++) sW[tid + i * 256] = W4[tid + i * 256];
    __syncthreads();

    int tx = tid & 31;   // cols 4*tx .. 4*tx+3
    int ty = tid >> 5;   // 8 row groups of 4 rows
    int row0 = blockIdx.x * 32 + ty * 4;

    const float4* Ar[4];
#pragma unroll
    for (int r = 0; r < 4; r++) {
        int rr = row0 + r;
        if (rr >= n) rr = n - 1;
        Ar[r] = (const float4*)(A + (size_t)rr * DIM);
    }

    float4 acc[4];
#pragma unroll
    for (int r = 0; r < 4; r++) acc[r] = make_float4(0.f, 0.f, 0.f, 0.f);

    for (int k4 = 0; k4 < 32; k4++) {
        float4 w0 = sW[(4 * k4 + 0) * 32 + tx];
        float4 w1 = sW[(4 * k4 + 1) * 32 + tx];
        float4 w2 = sW[(4 * k4 + 2) * 32 + tx];
        float4 w3 = sW[(4 * k4 + 3) * 32 + tx];
#pragma unroll
        for (int r = 0; r < 4; r++) {
            float4 a = Ar[r][k4];
            acc[r].x += a.x * w0.x + a.y * w1.x + a.z * w2.x + a.w * w3.x;
            acc[r].y += a.x * w0.y + a.y * w1.y + a.z * w2.y + a.w * w3.y;
            acc[r].z += a.x * w0.z + a.y * w1.z + a.z * w2.z + a.w * w3.z;
            acc[r].w += a.x * w0.w + a.y * w1.w + a.z * w2.w + a.w * w3.w;
        }
    }

#pragma unroll
    for (int r = 0; r < 4; r++) {
        int rr = row0 + r;
        if (rr < n) {
            __half2 h01 = __floats2half2_rn(acc[r].x, acc[r].y);
            __half2 h23 = __floats2half2_rn(acc[r].z, acc[r].w);
            uint2 pk;
            pk.x = *reinterpret_cast<unsigned int*>(&h01);
            pk.y = *reinterpret_cast<unsigned int*>(&h23);
            ((uint2*)(H + (size_t)rr * DIM))[tx] = pk;  // 8B/lane, 256B/row
        }
    }
}

// ===== CSR gather: out[d] = relu(bias + dinv[d]^2 h[d] + sum nrm*h[src]) =====
// fp16 table (256 B rows), fp32 accumulation. 32 lanes/node, 8-deep predicated
// pipeline. POOL: block-level segmented reduction over the SORTED batch array
// (one graph per 8-node block in ~98% of blocks) -> ~129 atomics/block.

__device__ __forceinline__ float2 unpack_h2(unsigned int u) {
    __half2 h = *reinterpret_cast<__half2*>(&u);
    return __half22float2(h);
}

template <bool POOL>
__global__ __launch_bounds__(256) void k_gather(const __half* __restrict__ H,
                                                const int* __restrict__ offs,
                                                const unsigned int* __restrict__ epack,
                                                const float* __restrict__ dinv,
                                                const float* __restrict__ bias,
                                                const int* __restrict__ batch,
                                                float* __restrict__ OUT,
                                                float* gsum, float* cnt, int n) {
    __shared__ float lpool[8 * 128];  // 4 KB (POOL reduction)
    __shared__ int sg[8];

    int idx = blockIdx.x * 256 + threadIdx.x;
    int i = idx >> 5;          // node; grid is exact (6250*8 == 50000)
    int lane = idx & 31;
    int w = threadIdx.x >> 5;  // node slot within block
    const uint2* H8 = (const uint2*)H;  // one row = 32 uint2 (8B/lane)

    float di = dinv[i];
    float sw = di * di;
    uint2 selfraw = H8[(size_t)i * 32 + lane];
    float2 s01 = unpack_h2(selfraw.x);
    float2 s23 = unpack_h2(selfraw.y);
    float4 acc = make_float4(sw * s01.x, sw * s01.y, sw * s23.x, sw * s23.y);

    int j0 = offs[i];
    int end = (i == n - 1) ? N_EDGES : offs[i + 1];

    for (int j = j0; j < end; j += 8) {
        int s[8];
        float wt[8];
#pragma unroll
        for (int k = 0; k < 8; k++) {
            int jj = j + k;
            bool valid = jj < end;
            int jc = valid ? jj : (end - 1);
            unsigned int pe = epack[jc];
            s[k] = (int)(pe & 0xffffu);
            __half_raw hr;
            hr.x = (unsigned short)(pe >> 16);
            float wv = __half2float(__half(hr));
            wt[k] = valid ? wv : 0.f;
        }
        uint2 v[8];
#pragma unroll
        for (int k = 0; k < 8; k++) v[k] = H8[(size_t)s[k] * 32 + lane];
#pragma unroll
        for (int k = 0; k < 8; k++) {
            float2 f01 = unpack_h2(v[k].x);
            float2 f23 = unpack_h2(v[k].y);
            acc.x += wt[k] * f01.x;
            acc.y += wt[k] * f01.y;
            acc.z += wt[k] * f23.x;
            acc.w += wt[k] * f23.y;
        }
    }

    float4 bb = ((const float4*)bias)[lane];
    acc.x = fmaxf(acc.x + bb.x, 0.f);
    acc.y = fmaxf(acc.y + bb.y, 0.f);
    acc.z = fmaxf(acc.z + bb.z, 0.f);
    acc.w = fmaxf(acc.w + bb.w, 0.f);

    if (POOL) {
        int g = batch[i];
        if (lane == 0) sg[w] = g;
        __syncthreads();
        bool uniform = true;
#pragma unroll
        for (int k = 0; k < 8; k++) uniform = uniform && (sg[k] == sg[0]);
        if (uniform) {
            ((float4*)(lpool + w * 128))[lane] = acc;
            __syncthreads();
            int t = threadIdx.x;
            if (t < 128) {
                float s = 0.f;
#pragma unroll
                for (int k = 0; k < 8; k++) s += lpool[k * 128 + t];
                atomicAdd(&gsum[sg[0] * DIM + t], s);
            }
            if (t == 0) atomicAdd(&cnt[sg[0]], 8.0f);
        } else {
            float* o = gsum + (size_t)g * DIM + lane * 4;
            atomicAdd(o + 0, acc.x);
            atomicAdd(o + 1, acc.y);
            atomicAdd(o + 2, acc.z);
            atomicAdd(o + 3, acc.w);
            if (lane == 0) atomicAdd(&cnt[g], 1.0f);
        }
    } else {
        ((float4*)OUT)[(size_t)i * 32 + lane] = acc;
    }
}

// ================= pooling scratch zero + classifier =================

__global__ __launch_bounds__(256) void k_zero(float* p, int n) {
    int i = blockIdx.x * 256 + threadIdx.x;
    if (i < n) p[i] = 0.f;
}

__global__ __launch_bounds__(128) void k_classifier(const float* __restrict__ gsum,
                                                    const float* __restrict__ cnt,
                                                    const float* __restrict__ Wc1,
                                                    const float* __restrict__ bc1,
                                                    const float* __restrict__ Wc2,
                                                    const float* __restrict__ bc2,
                                                    float* __restrict__ out) {
    int g = blockIdx.x;
    int t = threadIdx.x;  // 128
    __shared__ float gv[128];
    __shared__ float hid[128];
    float inv = 1.0f / fmaxf(cnt[g], 1.0f);
    gv[t] = gsum[(size_t)g * DIM + t] * inv;
    __syncthreads();
    float acc = bc1[t];
    for (int k = 0; k < 128; k++) acc += gv[k] * Wc1[k * 128 + t];
    hid[t] = fmaxf(acc, 0.f);
    __syncthreads();
    if (t < 4) {
        float o = bc2[t];
        for (int k = 0; k < 128; k++) o += hid[k] * Wc2[k * 4 + t];
        out[g * 4 + t] = o;
    }
}

// ================= launch =================

extern "C" void kernel_launch(void* const* d_in, const int* in_sizes, int n_in,
                              void* d_out, int out_size, void* d_ws, size_t ws_size,
                              hipStream_t stream) {
    const float* x     = (const float*)d_in[0];
    const int*   ei    = (const int*)d_in[1];  // [2, E]: src then dst
    const float* attr  = (const float*)d_in[2];
    // d_in[3] edge_weight: unused by reference
    const int*   batch = (const int*)d_in[4];
    const float* W0  = (const float*)d_in[5];
    const float* b0  = (const float*)d_in[6];
    const float* W1  = (const float*)d_in[7];
    const float* b1  = (const float*)d_in[8];
    const float* Wc1 = (const float*)d_in[9];
    const float* bc1 = (const float*)d_in[10];
    const float* Wc2 = (const float*)d_in[11];
    const float* bc2 = (const float*)d_in[12];
    float* out = (float*)d_out;

    char* ws = (char*)d_ws;
    __half*             bufH16   = (__half*)(ws + 0);                // 12,800,000
    float*              bufA     = (float*)(ws + 12800000);          // 25,600,000
    unsigned int*       epack    = (unsigned int*)(ws + 38400000);   //  3,200,000
    unsigned long long* packed   = (unsigned long long*)(ws + 41600000);  // 400,000
    unsigned short*     rank     = (unsigned short*)(ws + 42000000); //  1,600,000
    float*              dinv     = (float*)(ws + 43600000);          //    200,000
    int*                offs     = (int*)(ws + 43800000);            //    200,064
    int*                partials = (int*)(ws + 44000064);            //      1,024
    float*              gsum     = (float*)(ws + 44001088);          //     65,536
    float*              cnt      = (float*)(ws + 44066624);          //        512

    const int* src = ei;
    const int* dst = ei + N_EDGES;

    const int NB_N = (N_NODES + 255) / 256;   // 196
    const int NB_E = (N_EDGES + 255) / 256;   // 3125

    // CSR build: one u64 atomic/edge produces counts + attr-sums + ranks
    k_zero_u64<<<NB_N, 256, 0, stream>>>(packed, N_NODES);
    k_deg_hist<<<NB_E, 256, 0, stream>>>(dst, attr, packed, rank, N_EDGES);
    k_scan1<<<NB_N, 256, 0, stream>>>(packed, dinv, offs, partials, N_NODES);
    k_scan2<<<1, 256, 0, stream>>>(partials, NB_N);
    k_scan3<<<NB_N, 256, 0, stream>>>(offs, partials, N_NODES);
    k_scatter_edges<<<NB_E, 256, 0, stream>>>(src, dst, attr, dinv, offs, rank,
                                              epack, N_EDGES);

    // zero pool accumulators (ws is poisoned each call)
    k_zero<<<(NUM_GRAPHS * DIM + NUM_GRAPHS + 255) / 256, 256, 0, stream>>>(
        gsum, NUM_GRAPHS * DIM + NUM_GRAPHS);

    const int NB_G = (N_NODES * 32 + 255) / 256;  // 6250 (exact: 8 nodes/block)

    // layer 1: gemm(fp16 table) + gather(bias+relu fused)
    k_gemm16<<<(N_NODES + 31) / 32, 256, 0, stream>>>(x, W0, bufH16, N_NODES);
    k_gather<false><<<NB_G, 256, 0, stream>>>(bufH16, offs, epack, dinv, b0,
                                              batch, bufA, gsum, cnt, N_NODES);

    // layer 2: gemm(fp16 table) + gather(bias+relu+segmented-mean-pool fused)
    k_gemm16<<<(N_NODES + 31) / 32, 256, 0, stream>>>(bufA, W1, bufH16, N_NODES);
    k_gather<true><<<NB_G, 256, 0, stream>>>(bufH16, offs, epack, dinv, b1,
                                             batch, nullptr, gsum, cnt, N_NODES);

    // classifier
    k_classifier<<<NUM_GRAPHS, 128, 0, stream>>>(gsum, cnt, Wc1, bc1, Wc2, bc2, out);
}

// Round 9
// 286.429 us; speedup vs baseline: 2.4765x; 1.1169x over previous
//
#include <hip/hip_runtime.h>
#include <hip/hip_fp16.h>

#define N_NODES 50000
#define N_EDGES 800000
#define DIM 128
#define NUM_GRAPHS 128

#define ATTR_SCALE 33554432.0f        // 2^25 fixed-point for attr sums
#define ATTR_MASK  ((1ull << 40) - 1)

typedef _Float16 f16x8 __attribute__((ext_vector_type(8)));
typedef float f32x4 __attribute__((ext_vector_type(4)));

// ================= init: zero packed (count<<40 | attrsum) =================

__global__ __launch_bounds__(256) void k_zero_u64(unsigned long long* p, int n) {
    int i = blockIdx.x * 256 + threadIdx.x;
    if (i < n) p[i] = 0ull;
}

// ===== one u64 atomic per edge: counts AND attr-sum AND per-dst rank ======

__global__ __launch_bounds__(256) void k_deg_hist(const int* __restrict__ dst,
                                                  const float* __restrict__ attr,
                                                  unsigned long long* packed,
                                                  unsigned short* __restrict__ rank,
                                                  int E) {
    int e = blockIdx.x * 256 + threadIdx.x;
    if (e >= E) return;
    int d = dst[e];
    unsigned long long add =
        (1ull << 40) | (unsigned long long)(unsigned int)(attr[e] * ATTR_SCALE + 0.5f);
    unsigned long long old = atomicAdd(&packed[d], add);
    rank[e] = (unsigned short)(old >> 40);
}

// ===== scan1: per-block exclusive scan of counts; fused dinv + gsum zeroing ==

__global__ __launch_bounds__(256) void k_scan1(const unsigned long long* __restrict__ packed,
                                               float* __restrict__ dinv,
                                               int* __restrict__ offs,
                                               int* __restrict__ partials,
                                               float* __restrict__ gz, int n) {
    __shared__ int tmp[256];
    int t = threadIdx.x;
    int gid = blockIdx.x * 256 + t;
    // zero pool accumulators (gsum 16384 + cnt 128 floats, contiguous)
    if (gid < NUM_GRAPHS * DIM + NUM_GRAPHS) gz[gid] = 0.f;
    int v = 0;
    if (gid < n) {
        unsigned long long pk = packed[gid];
        v = (int)(pk >> 40);
        float deg = 1.0f + (float)(pk & ATTR_MASK) * (1.0f / ATTR_SCALE);
        dinv[gid] = rsqrtf(deg);  // deg >= 1 always (self-loop)
    }
    tmp[t] = v;
    __syncthreads();
    for (int off = 1; off < 256; off <<= 1) {
        int add = (t >= off) ? tmp[t - off] : 0;
        __syncthreads();
        tmp[t] += add;
        __syncthreads();
    }
    if (gid < n) offs[gid] = tmp[t] - v;  // exclusive within block
    if (t == 255) partials[blockIdx.x] = tmp[255];
}

// ===== scan3 (fused former scan2): every block scans partials in LDS ========

__global__ __launch_bounds__(256) void k_scan3(int* __restrict__ offs,
                                               const int* __restrict__ partials,
                                               int nb, int n) {
    __shared__ int tmp[256];
    int t = threadIdx.x;
    tmp[t] = (t < nb) ? partials[t] : 0;
    __syncthreads();
    for (int off = 1; off < 256; off <<= 1) {
        int add = (t >= off) ? tmp[t - off] : 0;
        __syncthreads();
        tmp[t] += add;
        __syncthreads();
    }
    int addv = (blockIdx.x == 0) ? 0 : tmp[blockIdx.x - 1];  // exclusive prefix
    int gid = blockIdx.x * 256 + t;
    if (gid < n) offs[gid] += addv;
}

// ===== scatter edges to dst-sorted array — NO atomics (rank precomputed) ===

__global__ __launch_bounds__(256) void k_scatter_edges(const int* __restrict__ src,
                                                       const int* __restrict__ dst,
                                                       const float* __restrict__ attr,
                                                       const float* __restrict__ dinv,
                                                       const int* __restrict__ offs,
                                                       const unsigned short* __restrict__ rank,
                                                       unsigned int* __restrict__ epack,
                                                       int E) {
    int e = blockIdx.x * 256 + threadIdx.x;
    if (e >= E) return;
    int s = src[e];
    int d = dst[e];
    int p = offs[d] + (int)rank[e];
    __half hn = __float2half_rn(dinv[s] * attr[e] * dinv[d]);
    unsigned short us = *reinterpret_cast<unsigned short*>(&hn);
    epack[p] = ((unsigned int)us << 16) | (unsigned int)s;
}

// ===== W prep: Wt[n][k] = fp16(W[k][n]) — 32 KB, stays L1/L2-hot ===========

__global__ __launch_bounds__(128) void k_prep_w(const float* __restrict__ W0,
                                                const float* __restrict__ W1,
                                                _Float16* __restrict__ Wt0,
                                                _Float16* __restrict__ Wt1) {
    int b = blockIdx.x;              // 256 blocks: (matrix, k-row)
    const float* W = (b & 1) ? W1 : W0;
    _Float16* Wt = (b & 1) ? Wt1 : Wt0;
    int k = b >> 1;
    int nn = threadIdx.x;            // 128
    Wt[(size_t)nn * 128 + k] = (_Float16)W[(size_t)k * 128 + nn];
}

// ===== MFMA f16 GEMM: H(fp16)[n x 128] = A(fp32) @ W =======================
// v_mfma_f32_16x16x32_f16. Layouts (HW-verified per guide):
//   A-frag: m = lane&15, k = quad*8 + j      [m120]
//   B-frag: n = lane&15, k = quad*8 + j  (Wt[n][k] pre-transposed)
//   C/D:    col = lane&15, row = quad*4 + reg [m89]
// Wave = 16 rows x 128 cols; block = 4 waves = 64 rows. No LDS, no barrier:
// B-frags read from the 32 KB global Wt (L1-resident after first iteration).

__global__ __launch_bounds__(256) void k_gemm_mfma(const float* __restrict__ A,
                                                   const _Float16* __restrict__ Wt,
                                                   __half* __restrict__ H, int n) {
    int tid = threadIdx.x;
    int w = tid >> 6, lane = tid & 63;
    int n15 = lane & 15, quad = lane >> 4;
    int row = blockIdx.x * 64 + w * 16 + n15;
    int rowc = row < n ? row : n - 1;
    const float4* Arow = (const float4*)(A + (size_t)rowc * DIM);

    f32x4 acc[8];
#pragma unroll
    for (int t = 0; t < 8; t++) acc[t] = (f32x4){0.f, 0.f, 0.f, 0.f};

#pragma unroll
    for (int c = 0; c < 4; c++) {
        float4 a0 = Arow[c * 8 + quad * 2];
        float4 a1 = Arow[c * 8 + quad * 2 + 1];
        f16x8 af;
        af[0] = (_Float16)a0.x; af[1] = (_Float16)a0.y;
        af[2] = (_Float16)a0.z; af[3] = (_Float16)a0.w;
        af[4] = (_Float16)a1.x; af[5] = (_Float16)a1.y;
        af[6] = (_Float16)a1.z; af[7] = (_Float16)a1.w;
#pragma unroll
        for (int t = 0; t < 8; t++) {
            f16x8 bf = *(const f16x8*)(Wt + (size_t)(t * 16 + n15) * 128 + c * 32 + quad * 8);
            acc[t] = __builtin_amdgcn_mfma_f32_16x16x32_f16(af, bf, acc[t], 0, 0, 0);
        }
    }

    int orow0 = blockIdx.x * 64 + w * 16 + quad * 4;
#pragma unroll
    for (int r = 0; r < 4; r++) {
        int orow = orow0 + r;
        if (orow < n) {
            __half* hp = H + (size_t)orow * DIM + n15;
#pragma unroll
            for (int t = 0; t < 8; t++) hp[t * 16] = __float2half_rn(acc[t][r]);
        }
    }
}

// ===== CSR gather: out[d] = relu(bias + dinv[d]^2 h[d] + sum nrm*h[src]) =====
// fp16 table (256 B rows), fp32 accumulation, 32 lanes/node, 8-deep predicated
// pipeline. POOL: block-level segmented reduction over sorted batch.

__device__ __forceinline__ float2 unpack_h2(unsigned int u) {
    __half2 h = *reinterpret_cast<__half2*>(&u);
    return __half22float2(h);
}

template <bool POOL>
__global__ __launch_bounds__(256) void k_gather(const __half* __restrict__ H,
                                                const int* __restrict__ offs,
                                                const unsigned int* __restrict__ epack,
                                                const float* __restrict__ dinv,
                                                const float* __restrict__ bias,
                                                const int* __restrict__ batch,
                                                float* __restrict__ OUT,
                                                float* gsum, float* cnt, int n) {
    __shared__ float lpool[8 * 128];  // 4 KB (POOL reduction)
    __shared__ int sg[8];

    int idx = blockIdx.x * 256 + threadIdx.x;
    int i = idx >> 5;          // node; grid exact (6250*8 == 50000)
    int lane = idx & 31;
    int w = threadIdx.x >> 5;
    const uint2* H8 = (const uint2*)H;

    float di = dinv[i];
    float sw = di * di;
    uint2 selfraw = H8[(size_t)i * 32 + lane];
    float2 s01 = unpack_h2(selfraw.x);
    float2 s23 = unpack_h2(selfraw.y);
    float4 acc = make_float4(sw * s01.x, sw * s01.y, sw * s23.x, sw * s23.y);

    int j0 = offs[i];
    int end = (i == n - 1) ? N_EDGES : offs[i + 1];

    for (int j = j0; j < end; j += 8) {
        int s[8];
        float wt[8];
#pragma unroll
        for (int k = 0; k < 8; k++) {
            int jj = j + k;
            bool valid = jj < end;
            int jc = valid ? jj : (end - 1);
            unsigned int pe = epack[jc];
            s[k] = (int)(pe & 0xffffu);
            __half_raw hr;
            hr.x = (unsigned short)(pe >> 16);
            float wv = __half2float(__half(hr));
            wt[k] = valid ? wv : 0.f;
        }
        uint2 v[8];
#pragma unroll
        for (int k = 0; k < 8; k++) v[k] = H8[(size_t)s[k] * 32 + lane];
#pragma unroll
        for (int k = 0; k < 8; k++) {
            float2 f01 = unpack_h2(v[k].x);
            float2 f23 = unpack_h2(v[k].y);
            acc.x += wt[k] * f01.x;
            acc.y += wt[k] * f01.y;
            acc.z += wt[k] * f23.x;
            acc.w += wt[k] * f23.y;
        }
    }

    float4 bb = ((const float4*)bias)[lane];
    acc.x = fmaxf(acc.x + bb.x, 0.f);
    acc.y = fmaxf(acc.y + bb.y, 0.f);
    acc.z = fmaxf(acc.z + bb.z, 0.f);
    acc.w = fmaxf(acc.w + bb.w, 0.f);

    if (POOL) {
        int g = batch[i];
        if (lane == 0) sg[w] = g;
        __syncthreads();
        bool uniform = true;
#pragma unroll
        for (int k = 0; k < 8; k++) uniform = uniform && (sg[k] == sg[0]);
        if (uniform) {
            ((float4*)(lpool + w * 128))[lane] = acc;
            __syncthreads();
            int t = threadIdx.x;
            if (t < 128) {
                float s = 0.f;
#pragma unroll
                for (int k = 0; k < 8; k++) s += lpool[k * 128 + t];
                atomicAdd(&gsum[sg[0] * DIM + t], s);
            }
            if (t == 0) atomicAdd(&cnt[sg[0]], 8.0f);
        } else {
            float* o = gsum + (size_t)g * DIM + lane * 4;
            atomicAdd(o + 0, acc.x);
            atomicAdd(o + 1, acc.y);
            atomicAdd(o + 2, acc.z);
            atomicAdd(o + 3, acc.w);
            if (lane == 0) atomicAdd(&cnt[g], 1.0f);
        }
    } else {
        ((float4*)OUT)[(size_t)i * 32 + lane] = acc;
    }
}

// ================= classifier =================

__global__ __launch_bounds__(128) void k_classifier(const float* __restrict__ gsum,
                                                    const float* __restrict__ cnt,
                                                    const float* __restrict__ Wc1,
                                                    const float* __restrict__ bc1,
                                                    const float* __restrict__ Wc2,
                                                    const float* __restrict__ bc2,
                                                    float* __restrict__ out) {
    int g = blockIdx.x;
    int t = threadIdx.x;  // 128
    __shared__ float gv[128];
    __shared__ float hid[128];
    float inv = 1.0f / fmaxf(cnt[g], 1.0f);
    gv[t] = gsum[(size_t)g * DIM + t] * inv;
    __syncthreads();
    float acc = bc1[t];
    for (int k = 0; k < 128; k++) acc += gv[k] * Wc1[k * 128 + t];
    hid[t] = fmaxf(acc, 0.f);
    __syncthreads();
    if (t < 4) {
        float o = bc2[t];
        for (int k = 0; k < 128; k++) o += hid[k] * Wc2[k * 4 + t];
        out[g * 4 + t] = o;
    }
}

// ================= launch =================

extern "C" void kernel_launch(void* const* d_in, const int* in_sizes, int n_in,
                              void* d_out, int out_size, void* d_ws, size_t ws_size,
                              hipStream_t stream) {
    const float* x     = (const float*)d_in[0];
    const int*   ei    = (const int*)d_in[1];  // [2, E]: src then dst
    const float* attr  = (const float*)d_in[2];
    // d_in[3] edge_weight: unused by reference
    const int*   batch = (const int*)d_in[4];
    const float* W0  = (const float*)d_in[5];
    const float* b0  = (const float*)d_in[6];
    const float* W1  = (const float*)d_in[7];
    const float* b1  = (const float*)d_in[8];
    const float* Wc1 = (const float*)d_in[9];
    const float* bc1 = (const float*)d_in[10];
    const float* Wc2 = (const float*)d_in[11];
    const float* bc2 = (const float*)d_in[12];
    float* out = (float*)d_out;

    char* ws = (char*)d_ws;
    __half*             bufH16   = (__half*)(ws + 0);                // 12,800,000
    float*              bufA     = (float*)(ws + 12800000);          // 25,600,000
    unsigned int*       epack    = (unsigned int*)(ws + 38400000);   //  3,200,000
    unsigned long long* packed   = (unsigned long long*)(ws + 41600000);  // 400,000
    unsigned short*     rank     = (unsigned short*)(ws + 42000000); //  1,600,000
    float*              dinv     = (float*)(ws + 43600000);          //    200,000
    int*                offs     = (int*)(ws + 43800000);            //    200,064
    int*                partials = (int*)(ws + 44000064);            //      1,024
    float*              gsum     = (float*)(ws + 44001088);          //     65,536
    float*              cnt      = (float*)(ws + 44066624);          //        512
    _Float16*           Wt0      = (_Float16*)(ws + 44067136);       //     32,768
    _Float16*           Wt1      = (_Float16*)(ws + 44099904);       //     32,768

    const int* src = ei;
    const int* dst = ei + N_EDGES;

    const int NB_N = (N_NODES + 255) / 256;   // 196
    const int NB_E = (N_EDGES + 255) / 256;   // 3125

    // CSR build: one u64 atomic/edge -> counts + attr-sums + ranks
    k_zero_u64<<<NB_N, 256, 0, stream>>>(packed, N_NODES);
    k_prep_w<<<256, 128, 0, stream>>>(W0, W1, Wt0, Wt1);
    k_deg_hist<<<NB_E, 256, 0, stream>>>(dst, attr, packed, rank, N_EDGES);
    k_scan1<<<NB_N, 256, 0, stream>>>(packed, dinv, offs, partials, gsum, N_NODES);
    k_scan3<<<NB_N, 256, 0, stream>>>(offs, partials, NB_N, N_NODES);
    k_scatter_edges<<<NB_E, 256, 0, stream>>>(src, dst, attr, dinv, offs, rank,
                                              epack, N_EDGES);

    const int NB_G = (N_NODES * 32 + 255) / 256;  // 6250 (exact: 8 nodes/block)
    const int NB_M = (N_NODES + 63) / 64;         // 782

    // layer 1: MFMA gemm(fp16 table) + gather(bias+relu fused)
    k_gemm_mfma<<<NB_M, 256, 0, stream>>>(x, Wt0, bufH16, N_NODES);
    k_gather<false><<<NB_G, 256, 0, stream>>>(bufH16, offs, epack, dinv, b0,
                                              batch, bufA, gsum, cnt, N_NODES);

    // layer 2: MFMA gemm + gather(bias+relu+segmented-mean-pool fused)
    k_gemm_mfma<<<NB_M, 256, 0, stream>>>(bufA, Wt1, bufH16, N_NODES);
    k_gather<true><<<NB_G, 256, 0, stream>>>(bufH16, offs, epack, dinv, b1,
                                             batch, nullptr, gsum, cnt, N_NODES);

    // classifier
    k_classifier<<<NUM_GRAPHS, 128, 0, stream>>>(gsum, cnt, Wc1, bc1, Wc2, bc2, out);
}

// Round 10
// 278.891 us; speedup vs baseline: 2.5435x; 1.0270x over previous
//
#include <hip/hip_runtime.h>
#include <hip/hip_fp16.h>

#define N_NODES 50000
#define N_EDGES 800000
#define DIM 128
#define NUM_GRAPHS 128
#define STRIDE 64                      // CSR slot stride (>= max in-degree)

#define ATTR_SCALE 33554432.0f         // 2^25 fixed-point for attr sums
#define ATTR_MASK  ((1ull << 40) - 1)

typedef _Float16 f16x8 __attribute__((ext_vector_type(8)));
typedef float f32x4 __attribute__((ext_vector_type(4)));

// ======= init: zero packed(count<<40|attrsum) and pool accumulators ========

__global__ __launch_bounds__(256) void k_zero(unsigned long long* packed,
                                              float* gz, int n) {
    int i = blockIdx.x * 256 + threadIdx.x;
    if (i < n) packed[i] = 0ull;
    if (i < NUM_GRAPHS * DIM + NUM_GRAPHS) gz[i] = 0.f;
}

// ===== fused CSR build: ONE pass over edges ================================
// u64 atomic gives count+attrsum+rank; fixed-stride slots need no offsets.
// Payload (attr:fp16 | src:u16) has no dinv dependency (dinv folded into H').

__global__ __launch_bounds__(256) void k_build(const int* __restrict__ src,
                                               const int* __restrict__ dst,
                                               const float* __restrict__ attr,
                                               unsigned long long* packed,
                                               unsigned int* __restrict__ epack,
                                               int E) {
    int e = blockIdx.x * 256 + threadIdx.x;
    if (e >= E) return;
    int d = dst[e];
    float a = attr[e];
    unsigned long long add =
        (1ull << 40) | (unsigned long long)(unsigned int)(a * ATTR_SCALE + 0.5f);
    unsigned long long old = atomicAdd(&packed[d], add);
    int rank = (int)(old >> 40);
    if (rank < STRIDE) {
        __half ha = __float2half_rn(a);
        unsigned short us = *reinterpret_cast<unsigned short*>(&ha);
        epack[d * STRIDE + rank] = ((unsigned int)us << 16) | (unsigned int)src[e];
    }
}

// ===== W prep: Wt[n][k] = fp16(W[k][n]) — 32 KB, stays L1/L2-hot ===========

__global__ __launch_bounds__(128) void k_prep_w(const float* __restrict__ W0,
                                                const float* __restrict__ W1,
                                                _Float16* __restrict__ Wt0,
                                                _Float16* __restrict__ Wt1) {
    int b = blockIdx.x;              // 256 blocks: (matrix, k-row)
    const float* W = (b & 1) ? W1 : W0;
    _Float16* Wt = (b & 1) ? Wt1 : Wt0;
    int k = b >> 1;
    int nn = threadIdx.x;            // 128
    Wt[(size_t)nn * 128 + k] = (_Float16)W[(size_t)k * 128 + nn];
}

// ===== MFMA f16 GEMM with dinv-folded epilogue: H'(fp16) = dinv[row]*(A@W) ==
// v_mfma_f32_16x16x32_f16. Layouts (HW-verified per guide):
//   A-frag: m = lane&15, k = quad*8 + j      [m120]
//   B-frag: n = lane&15, k = quad*8 + j  (Wt[n][k] pre-transposed)
//   C/D:    col = lane&15, row = quad*4 + reg [m89]
// dinv[row] computed inline from packed[] (u64 broadcast load + rsqrt).

__global__ __launch_bounds__(256) void k_gemm_mfma(const float* __restrict__ A,
                                                   const _Float16* __restrict__ Wt,
                                                   const unsigned long long* __restrict__ packed,
                                                   __half* __restrict__ H, int n) {
    int tid = threadIdx.x;
    int w = tid >> 6, lane = tid & 63;
    int n15 = lane & 15, quad = lane >> 4;
    int row = blockIdx.x * 64 + w * 16 + n15;
    int rowc = row < n ? row : n - 1;
    const float4* Arow = (const float4*)(A + (size_t)rowc * DIM);

    f32x4 acc[8];
#pragma unroll
    for (int t = 0; t < 8; t++) acc[t] = (f32x4){0.f, 0.f, 0.f, 0.f};

#pragma unroll
    for (int c = 0; c < 4; c++) {
        float4 a0 = Arow[c * 8 + quad * 2];
        float4 a1 = Arow[c * 8 + quad * 2 + 1];
        f16x8 af;
        af[0] = (_Float16)a0.x; af[1] = (_Float16)a0.y;
        af[2] = (_Float16)a0.z; af[3] = (_Float16)a0.w;
        af[4] = (_Float16)a1.x; af[5] = (_Float16)a1.y;
        af[6] = (_Float16)a1.z; af[7] = (_Float16)a1.w;
#pragma unroll
        for (int t = 0; t < 8; t++) {
            f16x8 bf = *(const f16x8*)(Wt + (size_t)(t * 16 + n15) * 128 + c * 32 + quad * 8);
            acc[t] = __builtin_amdgcn_mfma_f32_16x16x32_f16(af, bf, acc[t], 0, 0, 0);
        }
    }

    int orow0 = blockIdx.x * 64 + w * 16 + quad * 4;
#pragma unroll
    for (int r = 0; r < 4; r++) {
        int orow = orow0 + r;
        if (orow < n) {
            unsigned long long pk = packed[orow];
            float dv = rsqrtf(1.0f + (float)(pk & ATTR_MASK) * (1.0f / ATTR_SCALE));
            __half* hp = H + (size_t)orow * DIM + n15;
#pragma unroll
            for (int t = 0; t < 8; t++) hp[t * 16] = __float2half_rn(acc[t][r] * dv);
        }
    }
}

// ===== gather: out[d] = relu(dinv[d]*(H'[d] + sum attr_e*H'[src]) + bias) ===
// fp16 H' table (256 B rows), fp32 accumulation, 32 lanes/node, 8-deep
// predicated pipeline. count+dinv derived from packed[] inline (no offs).
// POOL: block-level segmented reduction over sorted batch.

__device__ __forceinline__ float2 unpack_h2(unsigned int u) {
    __half2 h = *reinterpret_cast<__half2*>(&u);
    return __half22float2(h);
}

template <bool POOL>
__global__ __launch_bounds__(256) void k_gather(const __half* __restrict__ H,
                                                const unsigned long long* __restrict__ packed,
                                                const unsigned int* __restrict__ epack,
                                                const float* __restrict__ bias,
                                                const int* __restrict__ batch,
                                                float* __restrict__ OUT,
                                                float* gsum, float* cnt, int n) {
    __shared__ float lpool[8 * 128];  // 4 KB (POOL reduction)
    __shared__ int sg[8];

    int idx = blockIdx.x * 256 + threadIdx.x;
    int i = idx >> 5;          // node; grid exact (6250*8 == 50000)
    int lane = idx & 31;
    int w = threadIdx.x >> 5;
    const uint2* H8 = (const uint2*)H;

    unsigned long long pk = packed[i];  // broadcast u64
    int cntE = (int)(pk >> 40);
    if (cntE > STRIDE) cntE = STRIDE;
    float dv = rsqrtf(1.0f + (float)(pk & ATTR_MASK) * (1.0f / ATTR_SCALE));

    uint2 selfraw = H8[(size_t)i * 32 + lane];
    float2 s01 = unpack_h2(selfraw.x);
    float2 s23 = unpack_h2(selfraw.y);
    float4 acc = make_float4(s01.x, s01.y, s23.x, s23.y);

    int j0 = i * STRIDE;
    int end = j0 + cntE;

    for (int j = j0; j < end; j += 8) {
        int s[8];
        float wt[8];
#pragma unroll
        for (int k = 0; k < 8; k++) {
            int jj = j + k;
            bool valid = jj < end;
            int jc = valid ? jj : (end - 1);
            unsigned int pe = epack[jc];
            s[k] = (int)(pe & 0xffffu);
            __half_raw hr;
            hr.x = (unsigned short)(pe >> 16);
            float wv = __half2float(__half(hr));
            wt[k] = valid ? wv : 0.f;
        }
        uint2 v[8];
#pragma unroll
        for (int k = 0; k < 8; k++) v[k] = H8[(size_t)s[k] * 32 + lane];
#pragma unroll
        for (int k = 0; k < 8; k++) {
            float2 f01 = unpack_h2(v[k].x);
            float2 f23 = unpack_h2(v[k].y);
            acc.x += wt[k] * f01.x;
            acc.y += wt[k] * f01.y;
            acc.z += wt[k] * f23.x;
            acc.w += wt[k] * f23.y;
        }
    }

    float4 bb = ((const float4*)bias)[lane];
    acc.x = fmaxf(acc.x * dv + bb.x, 0.f);
    acc.y = fmaxf(acc.y * dv + bb.y, 0.f);
    acc.z = fmaxf(acc.z * dv + bb.z, 0.f);
    acc.w = fmaxf(acc.w * dv + bb.w, 0.f);

    if (POOL) {
        int g = batch[i];
        if (lane == 0) sg[w] = g;
        __syncthreads();
        bool uniform = true;
#pragma unroll
        for (int k = 0; k < 8; k++) uniform = uniform && (sg[k] == sg[0]);
        if (uniform) {
            ((float4*)(lpool + w * 128))[lane] = acc;
            __syncthreads();
            int t = threadIdx.x;
            if (t < 128) {
                float s = 0.f;
#pragma unroll
                for (int k = 0; k < 8; k++) s += lpool[k * 128 + t];
                atomicAdd(&gsum[sg[0] * DIM + t], s);
            }
            if (t == 0) atomicAdd(&cnt[sg[0]], 8.0f);
        } else {
            float* o = gsum + (size_t)g * DIM + lane * 4;
            atomicAdd(o + 0, acc.x);
            atomicAdd(o + 1, acc.y);
            atomicAdd(o + 2, acc.z);
            atomicAdd(o + 3, acc.w);
            if (lane == 0) atomicAdd(&cnt[g], 1.0f);
        }
    } else {
        ((float4*)OUT)[(size_t)i * 32 + lane] = acc;
    }
}

// ================= classifier =================

__global__ __launch_bounds__(128) void k_classifier(const float* __restrict__ gsum,
                                                    const float* __restrict__ cnt,
                                                    const float* __restrict__ Wc1,
                                                    const float* __restrict__ bc1,
                                                    const float* __restrict__ Wc2,
                                                    const float* __restrict__ bc2,
                                                    float* __restrict__ out) {
    int g = blockIdx.x;
    int t = threadIdx.x;  // 128
    __shared__ float gv[128];
    __shared__ float hid[128];
    float inv = 1.0f / fmaxf(cnt[g], 1.0f);
    gv[t] = gsum[(size_t)g * DIM + t] * inv;
    __syncthreads();
    float acc = bc1[t];
    for (int k = 0; k < 128; k++) acc += gv[k] * Wc1[k * 128 + t];
    hid[t] = fmaxf(acc, 0.f);
    __syncthreads();
    if (t < 4) {
        float o = bc2[t];
        for (int k = 0; k < 128; k++) o += hid[k] * Wc2[k * 4 + t];
        out[g * 4 + t] = o;
    }
}

// ================= launch =================

extern "C" void kernel_launch(void* const* d_in, const int* in_sizes, int n_in,
                              void* d_out, int out_size, void* d_ws, size_t ws_size,
                              hipStream_t stream) {
    const float* x     = (const float*)d_in[0];
    const int*   ei    = (const int*)d_in[1];  // [2, E]: src then dst
    const float* attr  = (const float*)d_in[2];
    // d_in[3] edge_weight: unused by reference
    const int*   batch = (const int*)d_in[4];
    const float* W0  = (const float*)d_in[5];
    const float* b0  = (const float*)d_in[6];
    const float* W1  = (const float*)d_in[7];
    const float* b1  = (const float*)d_in[8];
    const float* Wc1 = (const float*)d_in[9];
    const float* bc1 = (const float*)d_in[10];
    const float* Wc2 = (const float*)d_in[11];
    const float* bc2 = (const float*)d_in[12];
    float* out = (float*)d_out;

    char* ws = (char*)d_ws;
    __half*             bufH16 = (__half*)(ws + 0);                  // 12,800,000
    float*              bufA   = (float*)(ws + 12800000);            // 25,600,000
    unsigned int*       epack  = (unsigned int*)(ws + 38400000);     // 12,800,000 (50000*64*4)
    unsigned long long* packed = (unsigned long long*)(ws + 51200000);  // 400,000
    float*              gsum   = (float*)(ws + 51600000);            //     65,536
    float*              cnt    = (float*)(ws + 51665536);            //        512
    _Float16*           Wt0    = (_Float16*)(ws + 51666048);         //     32,768
    _Float16*           Wt1    = (_Float16*)(ws + 51698816);         //     32,768

    const int* src = ei;
    const int* dst = ei + N_EDGES;

    const int NB_N = (N_NODES + 255) / 256;   // 196
    const int NB_E = (N_EDGES + 255) / 256;   // 3125
    const int NB_G = (N_NODES * 32 + 255) / 256;  // 6250 (exact: 8 nodes/block)
    const int NB_M = (N_NODES + 63) / 64;         // 782

    // init + W transpose + one-pass CSR build
    k_zero<<<NB_N, 256, 0, stream>>>(packed, gsum, N_NODES);
    k_prep_w<<<256, 128, 0, stream>>>(W0, W1, Wt0, Wt1);
    k_build<<<NB_E, 256, 0, stream>>>(src, dst, attr, packed, epack, N_EDGES);

    // layer 1: MFMA gemm (H' = dinv*h, fp16) + gather(bias+relu fused)
    k_gemm_mfma<<<NB_M, 256, 0, stream>>>(x, Wt0, packed, bufH16, N_NODES);
    k_gather<false><<<NB_G, 256, 0, stream>>>(bufH16, packed, epack, b0,
                                              batch, bufA, gsum, cnt, N_NODES);

    // layer 2: MFMA gemm + gather(bias+relu+segmented-mean-pool fused)
    k_gemm_mfma<<<NB_M, 256, 0, stream>>>(bufA, Wt1, packed, bufH16, N_NODES);
    k_gather<true><<<NB_G, 256, 0, stream>>>(bufH16, packed, epack, b1,
                                             batch, nullptr, gsum, cnt, N_NODES);

    // classifier
    k_classifier<<<NUM_GRAPHS, 128, 0, stream>>>(gsum, cnt, Wc1, bc1, Wc2, bc2, out);
}

// Round 12
// 276.280 us; speedup vs baseline: 2.5675x; 1.0094x over previous
//
#include <hip/hip_runtime.h>
#include <hip/hip_fp16.h>

#define N_NODES 50000
#define N_EDGES 800000
#define DIM 128
#define NUM_GRAPHS 128
#define STRIDE 64                      // CSR slot stride (>= max in-degree)

#define ATTR_SCALE 33554432.0f         // 2^25 fixed-point for attr sums
#define ATTR_MASK  ((1ull << 40) - 1)

typedef _Float16 f16x8 __attribute__((ext_vector_type(8)));
typedef float f32x4 __attribute__((ext_vector_type(4)));

// ===== fused CSR build + W-transpose (fat kernel) ==========================
// Blocks [0, NB_E): one u64 atomic per edge -> count+attrsum+rank; payload
// (attr:fp16 | src:u16) to fixed-stride slot. Blocks [NB_E, NB_E+128): prep
// Wt[m][n*128+k] = fp16(W[m][k*128+n]) (32 KB x2, L1/L2-hot for the gemms).

__global__ __launch_bounds__(256) void k_build(const int* __restrict__ src,
                                               const int* __restrict__ dst,
                                               const float* __restrict__ attr,
                                               const float* __restrict__ W0,
                                               const float* __restrict__ W1,
                                               unsigned long long* packed,
                                               unsigned int* __restrict__ epack,
                                               _Float16* __restrict__ Wt0,
                                               _Float16* __restrict__ Wt1,
                                               int E, int nbE) {
    int b = blockIdx.x;
    if (b >= nbE) {
        int idx = (b - nbE) * 256 + threadIdx.x;  // 32768 = 2 * 128 * 128
        int m = idx >> 14;
        int rem = idx & 16383;
        int n = rem >> 7;
        int k = rem & 127;
        const float* W = m ? W1 : W0;
        _Float16* Wt = m ? Wt1 : Wt0;
        Wt[(size_t)n * 128 + k] = (_Float16)W[(size_t)k * 128 + n];
        return;
    }
    int e = b * 256 + threadIdx.x;
    if (e >= E) return;
    int d = dst[e];
    float a = attr[e];
    unsigned long long add =
        (1ull << 40) | (unsigned long long)(unsigned int)(a * ATTR_SCALE + 0.5f);
    unsigned long long old = atomicAdd(&packed[d], add);
    int rank = (int)(old >> 40);
    if (rank < STRIDE) {
        __half ha = __float2half_rn(a);
        unsigned short us = *reinterpret_cast<unsigned short*>(&ha);
        epack[d * STRIDE + rank] = ((unsigned int)us << 16) | (unsigned int)src[e];
    }
}

// ===== MFMA f16 GEMM, operand-swapped: D = Wt . x  ========================
// v_mfma_f32_16x16x32_f16 with A-frag = Wt (weights), B-frag = x-row:
//   A-frag: m = lane&15 (out-feature), k = quad*8+j  -> Wt[(t*16+n15)*128 + k]
//   B-frag: n = lane&15 (node),        k = quad*8+j  -> A[node][c*32+quad*8+j]
//   C/D:    col = lane&15 = NODE, row = quad*4+reg = out-feature
// => each lane owns ONE node's features: packed uint2 (4 fp16) stores, and the
// dinv epilogue is one packed[] load per lane. AT = float (layer 1, cvt) or
// _Float16 (layer 2, direct 16 B loads).

template <typename AT>
__global__ __launch_bounds__(256) void k_gemm_mfma(const AT* __restrict__ A,
                                                   const _Float16* __restrict__ Wt,
                                                   const unsigned long long* __restrict__ packed,
                                                   __half* __restrict__ H, int n) {
    int tid = threadIdx.x;
    int w = tid >> 6, lane = tid & 63;
    int n15 = lane & 15, quad = lane >> 4;
    int node = blockIdx.x * 64 + w * 16 + n15;
    int nodec = node < n ? node : n - 1;
    const AT* Arow = A + (size_t)nodec * DIM;

    f32x4 acc[8];
#pragma unroll
    for (int t = 0; t < 8; t++) acc[t] = (f32x4){0.f, 0.f, 0.f, 0.f};

#pragma unroll
    for (int c = 0; c < 4; c++) {
        f16x8 bf;
        if constexpr (__is_same(AT, float)) {
            float4 a0 = ((const float4*)Arow)[c * 8 + quad * 2];
            float4 a1 = ((const float4*)Arow)[c * 8 + quad * 2 + 1];
            bf[0] = (_Float16)a0.x; bf[1] = (_Float16)a0.y;
            bf[2] = (_Float16)a0.z; bf[3] = (_Float16)a0.w;
            bf[4] = (_Float16)a1.x; bf[5] = (_Float16)a1.y;
            bf[6] = (_Float16)a1.z; bf[7] = (_Float16)a1.w;
        } else {
            bf = *(const f16x8*)(Arow + c * 32 + quad * 8);
        }
#pragma unroll
        for (int t = 0; t < 8; t++) {
            f16x8 af = *(const f16x8*)(Wt + (size_t)(t * 16 + n15) * 128 + c * 32 + quad * 8);
            acc[t] = __builtin_amdgcn_mfma_f32_16x16x32_f16(af, bf, acc[t], 0, 0, 0);
        }
    }

    if (node < n) {
        unsigned long long pk = packed[nodec];
        float dv = rsqrtf(1.0f + (float)(pk & ATTR_MASK) * (1.0f / ATTR_SCALE));
        __half* hp = H + (size_t)node * DIM + quad * 4;
#pragma unroll
        for (int t = 0; t < 8; t++) {
            __half2 h01 = __floats2half2_rn(acc[t][0] * dv, acc[t][1] * dv);
            __half2 h23 = __floats2half2_rn(acc[t][2] * dv, acc[t][3] * dv);
            uint2 pkd;
            pkd.x = *reinterpret_cast<unsigned int*>(&h01);
            pkd.y = *reinterpret_cast<unsigned int*>(&h23);
            *(uint2*)(hp + t * 16) = pkd;  // 8 B packed store
        }
    }
}

// ===== gather: out[d] = relu(dinv[d]*(H'[d] + sum attr_e*H'[src]) + bias) ===
// fp16 H' table (256 B rows), fp32 accumulation, 32 lanes/node, 8-deep
// predicated pipeline. count+dinv derived from packed[] inline.
// Non-pool output is fp16 (identical rounding to what gemm2 applied anyway).
// POOL: block-level segmented reduction over sorted batch.

__device__ __forceinline__ float2 unpack_h2(unsigned int u) {
    __half2 h = *reinterpret_cast<__half2*>(&u);
    return __half22float2(h);
}

template <bool POOL>
__global__ __launch_bounds__(256) void k_gather(const __half* __restrict__ H,
                                                const unsigned long long* __restrict__ packed,
                                                const unsigned int* __restrict__ epack,
                                                const float* __restrict__ bias,
                                                const int* __restrict__ batch,
                                                __half* __restrict__ OUT,
                                                float* gsum, float* cnt, int n) {
    __shared__ float lpool[8 * 128];  // 4 KB (POOL reduction)
    __shared__ int sg[8];

    int idx = blockIdx.x * 256 + threadIdx.x;
    int i = idx >> 5;          // node; grid exact (6250*8 == 50000)
    int lane = idx & 31;
    int w = threadIdx.x >> 5;
    const uint2* H8 = (const uint2*)H;

    unsigned long long pk = packed[i];  // broadcast u64
    int cntE = (int)(pk >> 40);
    if (cntE > STRIDE) cntE = STRIDE;
    float dv = rsqrtf(1.0f + (float)(pk & ATTR_MASK) * (1.0f / ATTR_SCALE));

    uint2 selfraw = H8[(size_t)i * 32 + lane];
    float2 s01 = unpack_h2(selfraw.x);
    float2 s23 = unpack_h2(selfraw.y);
    float4 acc = make_float4(s01.x, s01.y, s23.x, s23.y);

    int j0 = i * STRIDE;
    int end = j0 + cntE;

    for (int j = j0; j < end; j += 8) {
        int s[8];
        float wt[8];
#pragma unroll
        for (int k = 0; k < 8; k++) {
            int jj = j + k;
            bool valid = jj < end;
            int jc = valid ? jj : (end - 1);
            unsigned int pe = epack[jc];
            s[k] = (int)(pe & 0xffffu);
            __half_raw hr;
            hr.x = (unsigned short)(pe >> 16);
            float wv = __half2float(__half(hr));
            wt[k] = valid ? wv : 0.f;
        }
        uint2 v[8];
#pragma unroll
        for (int k = 0; k < 8; k++) v[k] = H8[(size_t)s[k] * 32 + lane];
#pragma unroll
        for (int k = 0; k < 8; k++) {
            float2 f01 = unpack_h2(v[k].x);
            float2 f23 = unpack_h2(v[k].y);
            acc.x += wt[k] * f01.x;
            acc.y += wt[k] * f01.y;
            acc.z += wt[k] * f23.x;
            acc.w += wt[k] * f23.y;
        }
    }

    float4 bb = ((const float4*)bias)[lane];
    acc.x = fmaxf(acc.x * dv + bb.x, 0.f);
    acc.y = fmaxf(acc.y * dv + bb.y, 0.f);
    acc.z = fmaxf(acc.z * dv + bb.z, 0.f);
    acc.w = fmaxf(acc.w * dv + bb.w, 0.f);

    if (POOL) {
        int g = batch[i];
        if (lane == 0) sg[w] = g;
        __syncthreads();
        bool uniform = true;
#pragma unroll
        for (int k = 0; k < 8; k++) uniform = uniform && (sg[k] == sg[0]);
        if (uniform) {
            ((float4*)(lpool + w * 128))[lane] = acc;
            __syncthreads();
            int t = threadIdx.x;
            if (t < 128) {
                float s = 0.f;
#pragma unroll
                for (int k = 0; k < 8; k++) s += lpool[k * 128 + t];
                atomicAdd(&gsum[sg[0] * DIM + t], s);
            }
            if (t == 0) atomicAdd(&cnt[sg[0]], 8.0f);
        } else {
            float* o = gsum + (size_t)g * DIM + lane * 4;
            atomicAdd(o + 0, acc.x);
            atomicAdd(o + 1, acc.y);
            atomicAdd(o + 2, acc.z);
            atomicAdd(o + 3, acc.w);
            if (lane == 0) atomicAdd(&cnt[g], 1.0f);
        }
    } else {
        __half2 p01 = __floats2half2_rn(acc.x, acc.y);
        __half2 p23 = __floats2half2_rn(acc.z, acc.w);
        uint2 o;
        o.x = *reinterpret_cast<unsigned int*>(&p01);
        o.y = *reinterpret_cast<unsigned int*>(&p23);
        ((uint2*)OUT)[(size_t)i * 32 + lane] = o;
    }
}

// ================= classifier =================

__global__ __launch_bounds__(128) void k_classifier(const float* __restrict__ gsum,
                                                    const float* __restrict__ cnt,
                                                    const float* __restrict__ Wc1,
                                                    const float* __restrict__ bc1,
                                                    const float* __restrict__ Wc2,
                                                    const float* __restrict__ bc2,
                                                    float* __restrict__ out) {
    int g = blockIdx.x;
    int t = threadIdx.x;  // 128
    __shared__ float gv[128];
    __shared__ float hid[128];
    float inv = 1.0f / fmaxf(cnt[g], 1.0f);
    gv[t] = gsum[(size_t)g * DIM + t] * inv;
    __syncthreads();
    float acc = bc1[t];
    for (int k = 0; k < 128; k++) acc += gv[k] * Wc1[k * 128 + t];
    hid[t] = fmaxf(acc, 0.f);
    __syncthreads();
    if (t < 4) {
        float o = bc2[t];
        for (int k = 0; k < 128; k++) o += hid[k] * Wc2[k * 4 + t];
        out[g * 4 + t] = o;
    }
}

// ================= launch =================

extern "C" void kernel_launch(void* const* d_in, const int* in_sizes, int n_in,
                              void* d_out, int out_size, void* d_ws, size_t ws_size,
                              hipStream_t stream) {
    const float* x     = (const float*)d_in[0];
    const int*   ei    = (const int*)d_in[1];  // [2, E]: src then dst
    const float* attr  = (const float*)d_in[2];
    // d_in[3] edge_weight: unused by reference
    const int*   batch = (const int*)d_in[4];
    const float* W0  = (const float*)d_in[5];
    const float* b0  = (const float*)d_in[6];
    const float* W1  = (const float*)d_in[7];
    const float* b1  = (const float*)d_in[8];
    const float* Wc1 = (const float*)d_in[9];
    const float* bc1 = (const float*)d_in[10];
    const float* Wc2 = (const float*)d_in[11];
    const float* bc2 = (const float*)d_in[12];
    float* out = (float*)d_out;

    char* ws = (char*)d_ws;
    __half*             bufH16 = (__half*)(ws + 0);                  // 12,800,000
    __half*             bufA16 = (__half*)(ws + 12800000);           // 12,800,000
    unsigned int*       epack  = (unsigned int*)(ws + 25600000);     // 12,800,000
    unsigned long long* packed = (unsigned long long*)(ws + 38400000);  // 400,000
    float*              gsum   = (float*)(ws + 38800000);            //     65,536
    float*              cnt    = (float*)(ws + 38865536);            //        512
    _Float16*           Wt0    = (_Float16*)(ws + 38866048);         //     32,768
    _Float16*           Wt1    = (_Float16*)(ws + 38898816);         //     32,768

    const int* src = ei;
    const int* dst = ei + N_EDGES;

    const int NB_E = (N_EDGES + 255) / 256;       // 3125
    const int NB_G = (N_NODES * 32 + 255) / 256;  // 6250 (exact: 8 nodes/block)
    const int NB_M = (N_NODES + 63) / 64;         // 782

    // zero packed+gsum+cnt (contiguous 466,048 B) without a kernel launch
    (void)hipMemsetAsync(ws + 38400000, 0, 466048, stream);

    // one-pass CSR build + W transpose (fat kernel)
    k_build<<<NB_E + 128, 256, 0, stream>>>(src, dst, attr, W0, W1, packed,
                                            epack, Wt0, Wt1, N_EDGES, NB_E);

    // layer 1: MFMA gemm (H' = dinv*(x@W0), fp16) + gather -> fp16 bufA
    k_gemm_mfma<float><<<NB_M, 256, 0, stream>>>(x, Wt0, packed, bufH16, N_NODES);
    k_gather<false><<<NB_G, 256, 0, stream>>>(bufH16, packed, epack, b0,
                                              batch, bufA16, gsum, cnt, N_NODES);

    // layer 2: MFMA gemm (fp16 A, direct loads) + gather w/ segmented pool
    k_gemm_mfma<_Float16><<<NB_M, 256, 0, stream>>>((const _Float16*)bufA16, Wt1,
                                                    packed, bufH16, N_NODES);
    k_gather<true><<<NB_G, 256, 0, stream>>>(bufH16, packed, epack, b1,
                                             batch, nullptr, gsum, cnt, N_NODES);

    // classifier
    k_classifier<<<NUM_GRAPHS, 128, 0, stream>>>(gsum, cnt, Wc1, bc1, Wc2, bc2, out);
}

// Round 13
// 273.379 us; speedup vs baseline: 2.5947x; 1.0106x over previous
//
#include <hip/hip_runtime.h>
#include <hip/hip_fp16.h>

#define N_NODES 50000
#define N_EDGES 800000
#define DIM 128
#define NUM_GRAPHS 128
#define STRIDE 64                      // CSR slot stride (>= max in-degree)

#define ATTR_SCALE 33554432.0f         // 2^25 fixed-point for attr sums
#define ATTR_MASK  ((1ull << 40) - 1)

typedef _Float16 f16x8 __attribute__((ext_vector_type(8)));
typedef float f32x4 __attribute__((ext_vector_type(4)));

// ===== fused CSR build + W-transpose, XCD-sliced ===========================
// 8 slice-copies of each 256-edge chunk; block commits only edges with
// dst%8 == (blockIdx&7). With round-robin block->XCD dispatch, slice==XCD,
// so every epack/packed line is written by ONE XCD: no cross-XCD line
// ping-pong (R12: 48.5 MB writeback for 13 MB of payload = the whole 53 us).
// Correct regardless of the actual mapping (each edge committed exactly once).
// Blocks [8*nbChunks, +128): Wt[m][n*128+k] = fp16(W[m][k*128+n]).

__global__ __launch_bounds__(256) void k_build(const int* __restrict__ src,
                                               const int* __restrict__ dst,
                                               const float* __restrict__ attr,
                                               const float* __restrict__ W0,
                                               const float* __restrict__ W1,
                                               unsigned long long* packed,
                                               unsigned int* __restrict__ epack,
                                               _Float16* __restrict__ Wt0,
                                               _Float16* __restrict__ Wt1,
                                               int E, int nbChunks) {
    int b = blockIdx.x;
    if (b >= nbChunks * 8) {
        int idx = (b - nbChunks * 8) * 256 + threadIdx.x;  // 32768 = 2*128*128
        int m = idx >> 14;
        int rem = idx & 16383;
        int n = rem >> 7;
        int k = rem & 127;
        const float* W = m ? W1 : W0;
        _Float16* Wt = m ? Wt1 : Wt0;
        Wt[(size_t)n * 128 + k] = (_Float16)W[(size_t)k * 128 + n];
        return;
    }
    int slice = b & 7;
    int e = (b >> 3) * 256 + threadIdx.x;
    if (e >= E) return;
    int d = dst[e];
    if ((d & 7) != slice) return;        // not this XCD's destination slice
    float a = attr[e];
    unsigned long long add =
        (1ull << 40) | (unsigned long long)(unsigned int)(a * ATTR_SCALE + 0.5f);
    unsigned long long old = atomicAdd(&packed[d], add);
    int rank = (int)(old >> 40);
    if (rank < STRIDE) {
        __half ha = __float2half_rn(a);
        unsigned short us = *reinterpret_cast<unsigned short*>(&ha);
        epack[d * STRIDE + rank] = ((unsigned int)us << 16) | (unsigned int)src[e];
    }
}

// ===== MFMA f16 GEMM, operand-swapped: D = Wt . x  ========================
// v_mfma_f32_16x16x32_f16 with A-frag = Wt (weights), B-frag = x-row:
//   A-frag: m = lane&15 (out-feature), k = quad*8+j  -> Wt[(t*16+n15)*128 + k]
//   B-frag: n = lane&15 (node),        k = quad*8+j  -> A[node][c*32+quad*8+j]
//   C/D:    col = lane&15 = NODE, row = quad*4+reg = out-feature
// => each lane owns ONE node's features: packed uint2 stores; dinv epilogue is
// one packed[] load per lane. AT = float (layer 1) or _Float16 (layer 2).

template <typename AT>
__global__ __launch_bounds__(256) void k_gemm_mfma(const AT* __restrict__ A,
                                                   const _Float16* __restrict__ Wt,
                                                   const unsigned long long* __restrict__ packed,
                                                   __half* __restrict__ H, int n) {
    int tid = threadIdx.x;
    int w = tid >> 6, lane = tid & 63;
    int n15 = lane & 15, quad = lane >> 4;
    int node = blockIdx.x * 64 + w * 16 + n15;
    int nodec = node < n ? node : n - 1;
    const AT* Arow = A + (size_t)nodec * DIM;

    f32x4 acc[8];
#pragma unroll
    for (int t = 0; t < 8; t++) acc[t] = (f32x4){0.f, 0.f, 0.f, 0.f};

#pragma unroll
    for (int c = 0; c < 4; c++) {
        f16x8 bf;
        if constexpr (__is_same(AT, float)) {
            float4 a0 = ((const float4*)Arow)[c * 8 + quad * 2];
            float4 a1 = ((const float4*)Arow)[c * 8 + quad * 2 + 1];
            bf[0] = (_Float16)a0.x; bf[1] = (_Float16)a0.y;
            bf[2] = (_Float16)a0.z; bf[3] = (_Float16)a0.w;
            bf[4] = (_Float16)a1.x; bf[5] = (_Float16)a1.y;
            bf[6] = (_Float16)a1.z; bf[7] = (_Float16)a1.w;
        } else {
            bf = *(const f16x8*)(Arow + c * 32 + quad * 8);
        }
#pragma unroll
        for (int t = 0; t < 8; t++) {
            f16x8 af = *(const f16x8*)(Wt + (size_t)(t * 16 + n15) * 128 + c * 32 + quad * 8);
            acc[t] = __builtin_amdgcn_mfma_f32_16x16x32_f16(af, bf, acc[t], 0, 0, 0);
        }
    }

    if (node < n) {
        unsigned long long pk = packed[nodec];
        float dv = rsqrtf(1.0f + (float)(pk & ATTR_MASK) * (1.0f / ATTR_SCALE));
        __half* hp = H + (size_t)node * DIM + quad * 4;
#pragma unroll
        for (int t = 0; t < 8; t++) {
            __half2 h01 = __floats2half2_rn(acc[t][0] * dv, acc[t][1] * dv);
            __half2 h23 = __floats2half2_rn(acc[t][2] * dv, acc[t][3] * dv);
            uint2 pkd;
            pkd.x = *reinterpret_cast<unsigned int*>(&h01);
            pkd.y = *reinterpret_cast<unsigned int*>(&h23);
            *(uint2*)(hp + t * 16) = pkd;  // 8 B packed store
        }
    }
}

// ===== gather: out[d] = relu(dinv[d]*(H'[d] + sum attr_e*H'[src]) + bias) ===
// fp16 H' table (256 B rows), fp32 accumulation, 32 lanes/node, 8-deep
// predicated pipeline. count+dinv derived from packed[] inline.
// POOL: block-level segmented reduction over sorted batch.

__device__ __forceinline__ float2 unpack_h2(unsigned int u) {
    __half2 h = *reinterpret_cast<__half2*>(&u);
    return __half22float2(h);
}

template <bool POOL>
__global__ __launch_bounds__(256) void k_gather(const __half* __restrict__ H,
                                                const unsigned long long* __restrict__ packed,
                                                const unsigned int* __restrict__ epack,
                                                const float* __restrict__ bias,
                                                const int* __restrict__ batch,
                                                __half* __restrict__ OUT,
                                                float* gsum, float* cnt, int n) {
    __shared__ float lpool[8 * 128];  // 4 KB (POOL reduction)
    __shared__ int sg[8];

    int idx = blockIdx.x * 256 + threadIdx.x;
    int i = idx >> 5;          // node; grid exact (6250*8 == 50000)
    int lane = idx & 31;
    int w = threadIdx.x >> 5;
    const uint2* H8 = (const uint2*)H;

    unsigned long long pk = packed[i];  // broadcast u64
    int cntE = (int)(pk >> 40);
    if (cntE > STRIDE) cntE = STRIDE;
    float dv = rsqrtf(1.0f + (float)(pk & ATTR_MASK) * (1.0f / ATTR_SCALE));

    uint2 selfraw = H8[(size_t)i * 32 + lane];
    float2 s01 = unpack_h2(selfraw.x);
    float2 s23 = unpack_h2(selfraw.y);
    float4 acc = make_float4(s01.x, s01.y, s23.x, s23.y);

    int j0 = i * STRIDE;
    int end = j0 + cntE;

    for (int j = j0; j < end; j += 8) {
        int s[8];
        float wt[8];
#pragma unroll
        for (int k = 0; k < 8; k++) {
            int jj = j + k;
            bool valid = jj < end;
            int jc = valid ? jj : (end - 1);
            unsigned int pe = epack[jc];
            s[k] = (int)(pe & 0xffffu);
            __half_raw hr;
            hr.x = (unsigned short)(pe >> 16);
            float wv = __half2float(__half(hr));
            wt[k] = valid ? wv : 0.f;
        }
        uint2 v[8];
#pragma unroll
        for (int k = 0; k < 8; k++) v[k] = H8[(size_t)s[k] * 32 + lane];
#pragma unroll
        for (int k = 0; k < 8; k++) {
            float2 f01 = unpack_h2(v[k].x);
            float2 f23 = unpack_h2(v[k].y);
            acc.x += wt[k] * f01.x;
            acc.y += wt[k] * f01.y;
            acc.z += wt[k] * f23.x;
            acc.w += wt[k] * f23.y;
        }
    }

    float4 bb = ((const float4*)bias)[lane];
    acc.x = fmaxf(acc.x * dv + bb.x, 0.f);
    acc.y = fmaxf(acc.y * dv + bb.y, 0.f);
    acc.z = fmaxf(acc.z * dv + bb.z, 0.f);
    acc.w = fmaxf(acc.w * dv + bb.w, 0.f);

    if (POOL) {
        int g = batch[i];
        if (lane == 0) sg[w] = g;
        __syncthreads();
        bool uniform = true;
#pragma unroll
        for (int k = 0; k < 8; k++) uniform = uniform && (sg[k] == sg[0]);
        if (uniform) {
            ((float4*)(lpool + w * 128))[lane] = acc;
            __syncthreads();
            int t = threadIdx.x;
            if (t < 128) {
                float s = 0.f;
#pragma unroll
                for (int k = 0; k < 8; k++) s += lpool[k * 128 + t];
                atomicAdd(&gsum[sg[0] * DIM + t], s);
            }
            if (t == 0) atomicAdd(&cnt[sg[0]], 8.0f);
        } else {
            float* o = gsum + (size_t)g * DIM + lane * 4;
            atomicAdd(o + 0, acc.x);
            atomicAdd(o + 1, acc.y);
            atomicAdd(o + 2, acc.z);
            atomicAdd(o + 3, acc.w);
            if (lane == 0) atomicAdd(&cnt[g], 1.0f);
        }
    } else {
        __half2 p01 = __floats2half2_rn(acc.x, acc.y);
        __half2 p23 = __floats2half2_rn(acc.z, acc.w);
        uint2 o;
        o.x = *reinterpret_cast<unsigned int*>(&p01);
        o.y = *reinterpret_cast<unsigned int*>(&p23);
        ((uint2*)OUT)[(size_t)i * 32 + lane] = o;
    }
}

// ================= classifier =================

__global__ __launch_bounds__(128) void k_classifier(const float* __restrict__ gsum,
                                                    const float* __restrict__ cnt,
                                                    const float* __restrict__ Wc1,
                                                    const float* __restrict__ bc1,
                                                    const float* __restrict__ Wc2,
                                                    const float* __restrict__ bc2,
                                                    float* __restrict__ out) {
    int g = blockIdx.x;
    int t = threadIdx.x;  // 128
    __shared__ float gv[128];
    __shared__ float hid[128];
    float inv = 1.0f / fmaxf(cnt[g], 1.0f);
    gv[t] = gsum[(size_t)g * DIM + t] * inv;
    __syncthreads();
    float acc = bc1[t];
    for (int k = 0; k < 128; k++) acc += gv[k] * Wc1[k * 128 + t];
    hid[t] = fmaxf(acc, 0.f);
    __syncthreads();
    if (t < 4) {
        float o = bc2[t];
        for (int k = 0; k < 128; k++) o += hid[k] * Wc2[k * 4 + t];
        out[g * 4 + t] = o;
    }
}

// ================= launch =================

extern "C" void kernel_launch(void* const* d_in, const int* in_sizes, int n_in,
                              void* d_out, int out_size, void* d_ws, size_t ws_size,
                              hipStream_t stream) {
    const float* x     = (const float*)d_in[0];
    const int*   ei    = (const int*)d_in[1];  // [2, E]: src then dst
    const float* attr  = (const float*)d_in[2];
    // d_in[3] edge_weight: unused by reference
    const int*   batch = (const int*)d_in[4];
    const float* W0  = (const float*)d_in[5];
    const float* b0  = (const float*)d_in[6];
    const float* W1  = (const float*)d_in[7];
    const float* b1  = (const float*)d_in[8];
    const float* Wc1 = (const float*)d_in[9];
    const float* bc1 = (const float*)d_in[10];
    const float* Wc2 = (const float*)d_in[11];
    const float* bc2 = (const float*)d_in[12];
    float* out = (float*)d_out;

    char* ws = (char*)d_ws;
    __half*             bufH16 = (__half*)(ws + 0);                  // 12,800,000
    __half*             bufA16 = (__half*)(ws + 12800000);           // 12,800,000
    unsigned int*       epack  = (unsigned int*)(ws + 25600000);     // 12,800,000
    unsigned long long* packed = (unsigned long long*)(ws + 38400000);  // 400,000
    float*              gsum   = (float*)(ws + 38800000);            //     65,536
    float*              cnt    = (float*)(ws + 38865536);            //        512
    _Float16*           Wt0    = (_Float16*)(ws + 38866048);         //     32,768
    _Float16*           Wt1    = (_Float16*)(ws + 38898816);         //     32,768

    const int* src = ei;
    const int* dst = ei + N_EDGES;

    const int NB_C = (N_EDGES + 255) / 256;       // 3125 chunks
    const int NB_G = (N_NODES * 32 + 255) / 256;  // 6250 (exact: 8 nodes/block)
    const int NB_M = (N_NODES + 63) / 64;         // 782

    // zero packed+gsum+cnt (contiguous 466,048 B) without a kernel launch
    (void)hipMemsetAsync(ws + 38400000, 0, 466048, stream);

    // XCD-sliced one-pass CSR build + W transpose
    k_build<<<NB_C * 8 + 128, 256, 0, stream>>>(src, dst, attr, W0, W1, packed,
                                                epack, Wt0, Wt1, N_EDGES, NB_C);

    // layer 1: MFMA gemm (H' = dinv*(x@W0), fp16) + gather -> fp16 bufA
    k_gemm_mfma<float><<<NB_M, 256, 0, stream>>>(x, Wt0, packed, bufH16, N_NODES);
    k_gather<false><<<NB_G, 256, 0, stream>>>(bufH16, packed, epack, b0,
                                              batch, bufA16, gsum, cnt, N_NODES);

    // layer 2: MFMA gemm (fp16 A, direct loads) + gather w/ segmented pool
    k_gemm_mfma<_Float16><<<NB_M, 256, 0, stream>>>((const _Float16*)bufA16, Wt1,
                                                    packed, bufH16, N_NODES);
    k_gather<true><<<NB_G, 256, 0, stream>>>(bufH16, packed, epack, b1,
                                             batch, nullptr, gsum, cnt, N_NODES);

    // classifier
    k_classifier<<<NUM_GRAPHS, 128, 0, stream>>>(gsum, cnt, Wc1, bc1, Wc2, bc2, out);
}

// Round 14
// 271.959 us; speedup vs baseline: 2.6083x; 1.0052x over previous
//
#include <hip/hip_runtime.h>
#include <hip/hip_fp16.h>

#define N_NODES 50000
#define N_EDGES 800000
#define DIM 128
#define NUM_GRAPHS 128
#define STRIDE 64                      // CSR slot stride (>= max in-degree)

#define ATTR_SCALE 33554432.0f         // 2^25 fixed-point for attr sums
#define ATTR_MASK  ((1ull << 40) - 1)

typedef _Float16 f16x8 __attribute__((ext_vector_type(8)));
typedef float f32x4 __attribute__((ext_vector_type(4)));

// ===== fused CSR build + W-transpose, XCD-sliced (unchanged from R13) ======

__global__ __launch_bounds__(256) void k_build(const int* __restrict__ src,
                                               const int* __restrict__ dst,
                                               const float* __restrict__ attr,
                                               const float* __restrict__ W0,
                                               const float* __restrict__ W1,
                                               unsigned long long* packed,
                                               unsigned int* __restrict__ epack,
                                               _Float16* __restrict__ Wt0,
                                               _Float16* __restrict__ Wt1,
                                               int E, int nbChunks) {
    int b = blockIdx.x;
    if (b >= nbChunks * 8) {
        int idx = (b - nbChunks * 8) * 256 + threadIdx.x;  // 32768 = 2*128*128
        int m = idx >> 14;
        int rem = idx & 16383;
        int n = rem >> 7;
        int k = rem & 127;
        const float* W = m ? W1 : W0;
        _Float16* Wt = m ? Wt1 : Wt0;
        Wt[(size_t)n * 128 + k] = (_Float16)W[(size_t)k * 128 + n];
        return;
    }
    int slice = b & 7;
    int e = (b >> 3) * 256 + threadIdx.x;
    if (e >= E) return;
    int d = dst[e];
    if ((d & 7) != slice) return;
    float a = attr[e];
    unsigned long long add =
        (1ull << 40) | (unsigned long long)(unsigned int)(a * ATTR_SCALE + 0.5f);
    unsigned long long old = atomicAdd(&packed[d], add);
    int rank = (int)(old >> 40);
    if (rank < STRIDE) {
        __half ha = __float2half_rn(a);
        unsigned short us = *reinterpret_cast<unsigned short*>(&ha);
        epack[d * STRIDE + rank] = ((unsigned int)us << 16) | (unsigned int)src[e];
    }
}

// ===== MFMA f16 GEMM, operand-swapped (unchanged from R13) =================

template <typename AT>
__global__ __launch_bounds__(256) void k_gemm_mfma(const AT* __restrict__ A,
                                                   const _Float16* __restrict__ Wt,
                                                   const unsigned long long* __restrict__ packed,
                                                   __half* __restrict__ H, int n) {
    int tid = threadIdx.x;
    int w = tid >> 6, lane = tid & 63;
    int n15 = lane & 15, quad = lane >> 4;
    int node = blockIdx.x * 64 + w * 16 + n15;
    int nodec = node < n ? node : n - 1;
    const AT* Arow = A + (size_t)nodec * DIM;

    f32x4 acc[8];
#pragma unroll
    for (int t = 0; t < 8; t++) acc[t] = (f32x4){0.f, 0.f, 0.f, 0.f};

#pragma unroll
    for (int c = 0; c < 4; c++) {
        f16x8 bf;
        if constexpr (__is_same(AT, float)) {
            float4 a0 = ((const float4*)Arow)[c * 8 + quad * 2];
            float4 a1 = ((const float4*)Arow)[c * 8 + quad * 2 + 1];
            bf[0] = (_Float16)a0.x; bf[1] = (_Float16)a0.y;
            bf[2] = (_Float16)a0.z; bf[3] = (_Float16)a0.w;
            bf[4] = (_Float16)a1.x; bf[5] = (_Float16)a1.y;
            bf[6] = (_Float16)a1.z; bf[7] = (_Float16)a1.w;
        } else {
            bf = *(const f16x8*)(Arow + c * 32 + quad * 8);
        }
#pragma unroll
        for (int t = 0; t < 8; t++) {
            f16x8 af = *(const f16x8*)(Wt + (size_t)(t * 16 + n15) * 128 + c * 32 + quad * 8);
            acc[t] = __builtin_amdgcn_mfma_f32_16x16x32_f16(af, bf, acc[t], 0, 0, 0);
        }
    }

    if (node < n) {
        unsigned long long pk = packed[nodec];
        float dv = rsqrtf(1.0f + (float)(pk & ATTR_MASK) * (1.0f / ATTR_SCALE));
        __half* hp = H + (size_t)node * DIM + quad * 4;
#pragma unroll
        for (int t = 0; t < 8; t++) {
            __half2 h01 = __floats2half2_rn(acc[t][0] * dv, acc[t][1] * dv);
            __half2 h23 = __floats2half2_rn(acc[t][2] * dv, acc[t][3] * dv);
            uint2 pkd;
            pkd.x = *reinterpret_cast<unsigned int*>(&h01);
            pkd.y = *reinterpret_cast<unsigned int*>(&h23);
            *(uint2*)(hp + t * 16) = pkd;
        }
    }
}

// ===== COLUMN-SLICED gather =================================================
// 8 lanes per node, column-group cg = blockIdx&3 -> each group reads exactly
// ONE 64 B line (uint2/lane x 8) of the 256 B row; with round-robin block->XCD
// each XCD touches a 3.2 MB column slice (fits 4 MB L2; avg latency drops at
// the fixed per-CU outstanding-line cap). 8-deep predicated pipeline.
// POOL: 32-node blocks; sorted batch => <=2 graph-runs per block, LDS-reduced;
// pathological third graph falls back to per-node atomics.

__device__ __forceinline__ float2 unpack_h2(unsigned int u) {
    __half2 h = *reinterpret_cast<__half2*>(&u);
    return __half22float2(h);
}

template <bool POOL>
__global__ __launch_bounds__(256) void k_gather(const __half* __restrict__ H,
                                                const unsigned long long* __restrict__ packed,
                                                const unsigned int* __restrict__ epack,
                                                const float* __restrict__ bias,
                                                const int* __restrict__ batch,
                                                __half* __restrict__ OUT,
                                                float* gsum, float* cnt, int n) {
    int cg = blockIdx.x & 3;           // column group (XCD-affine)
    int nb = blockIdx.x >> 2;          // node-block (32 nodes)
    int slot = threadIdx.x >> 3;       // node slot [0,32)
    int ln = threadIdx.x & 7;          // lane in group [0,8)
    int i = nb * 32 + slot;
    bool valid = i < n;
    int ic = valid ? i : n - 1;
    int colq = cg * 8 + ln;            // uint2 index within row [0,32)
    const uint2* H8 = (const uint2*)H;

    unsigned long long pk = packed[ic];
    int cntE = valid ? (int)(pk >> 40) : 0;
    if (cntE > STRIDE) cntE = STRIDE;
    float dv = rsqrtf(1.0f + (float)(pk & ATTR_MASK) * (1.0f / ATTR_SCALE));

    uint2 selfraw = H8[(size_t)ic * 32 + colq];
    float2 s01 = unpack_h2(selfraw.x);
    float2 s23 = unpack_h2(selfraw.y);
    float4 acc = make_float4(s01.x, s01.y, s23.x, s23.y);

    int j0 = ic * STRIDE;
    int end = j0 + cntE;

    for (int j = j0; j < end; j += 8) {
        int s[8];
        float wt[8];
#pragma unroll
        for (int k = 0; k < 8; k++) {
            int jj = j + k;
            bool v2 = jj < end;
            int jc = v2 ? jj : (end - 1);
            unsigned int pe = epack[jc];
            s[k] = (int)(pe & 0xffffu);
            __half_raw hr;
            hr.x = (unsigned short)(pe >> 16);
            wt[k] = v2 ? __half2float(__half(hr)) : 0.f;
        }
        uint2 v[8];
#pragma unroll
        for (int k = 0; k < 8; k++) v[k] = H8[(size_t)s[k] * 32 + colq];
#pragma unroll
        for (int k = 0; k < 8; k++) {
            float2 f01 = unpack_h2(v[k].x);
            float2 f23 = unpack_h2(v[k].y);
            acc.x += wt[k] * f01.x;
            acc.y += wt[k] * f01.y;
            acc.z += wt[k] * f23.x;
            acc.w += wt[k] * f23.y;
        }
    }

    float4 bb = ((const float4*)bias)[colq];
    acc.x = fmaxf(acc.x * dv + bb.x, 0.f);
    acc.y = fmaxf(acc.y * dv + bb.y, 0.f);
    acc.z = fmaxf(acc.z * dv + bb.z, 0.f);
    acc.w = fmaxf(acc.w * dv + bb.w, 0.f);

    if constexpr (POOL) {
        __shared__ float lpool[32 * 32];  // 32 nodes x 32 feats (this cg)
        __shared__ int sg[32];
        __shared__ int meta[4];           // gA, gB, cntA, cntB
        if (ln == 0) sg[slot] = valid ? batch[ic] : -1;
        __syncthreads();
        if (threadIdx.x == 0) {
            int nv = n - nb * 32; if (nv > 32) nv = 32;
            int gA = sg[0];
            int gB = sg[nv - 1];
            int cA = 0, cB = 0;
            for (int k2 = 0; k2 < nv; k2++) {
                if (sg[k2] == gA) cA++;
                else if (sg[k2] == gB) cB++;
            }
            meta[0] = gA; meta[1] = gB; meta[2] = cA; meta[3] = cB;
        }
        __syncthreads();
        int gA = meta[0], gB = meta[1];
        int myg = valid ? sg[slot] : -2;

        // pass A (covers whole block when uniform)
        bool inA = valid && (myg == gA);
        ((float4*)(lpool + slot * 32))[ln] =
            inA ? acc : make_float4(0.f, 0.f, 0.f, 0.f);
        __syncthreads();
        if (threadIdx.x < 32) {
            float ssum = 0.f;
#pragma unroll
            for (int k2 = 0; k2 < 32; k2++) ssum += lpool[k2 * 32 + threadIdx.x];
            atomicAdd(&gsum[gA * DIM + cg * 32 + threadIdx.x], ssum);
        }
        if (threadIdx.x == 0 && cg == 0) atomicAdd(&cnt[gA], (float)meta[2]);

        // pass B (boundary block: second graph run)
        if (gB != gA) {
            __syncthreads();
            bool inB = valid && (myg == gB);
            ((float4*)(lpool + slot * 32))[ln] =
                inB ? acc : make_float4(0.f, 0.f, 0.f, 0.f);
            __syncthreads();
            if (threadIdx.x < 32) {
                float ssum = 0.f;
#pragma unroll
                for (int k2 = 0; k2 < 32; k2++) ssum += lpool[k2 * 32 + threadIdx.x];
                atomicAdd(&gsum[gB * DIM + cg * 32 + threadIdx.x], ssum);
            }
            if (threadIdx.x == 0 && cg == 0) atomicAdd(&cnt[gB], (float)meta[3]);
        }

        // ultra-rare: a graph strictly inside the block (size < 32)
        if (valid && myg != gA && myg != gB) {
            float* o = gsum + (size_t)myg * DIM + cg * 32 + ln * 4;
            atomicAdd(o + 0, acc.x);
            atomicAdd(o + 1, acc.y);
            atomicAdd(o + 2, acc.z);
            atomicAdd(o + 3, acc.w);
            if (ln == 0 && cg == 0) atomicAdd(&cnt[myg], 1.0f);
        }
    } else {
        if (valid) {
            __half2 p01 = __floats2half2_rn(acc.x, acc.y);
            __half2 p23 = __floats2half2_rn(acc.z, acc.w);
            uint2 o;
            o.x = *reinterpret_cast<unsigned int*>(&p01);
            o.y = *reinterpret_cast<unsigned int*>(&p23);
            ((uint2*)OUT)[(size_t)i * 32 + colq] = o;
        }
    }
}

// ================= classifier =================

__global__ __launch_bounds__(128) void k_classifier(const float* __restrict__ gsum,
                                                    const float* __restrict__ cnt,
                                                    const float* __restrict__ Wc1,
                                                    const float* __restrict__ bc1,
                                                    const float* __restrict__ Wc2,
                                                    const float* __restrict__ bc2,
                                                    float* __restrict__ out) {
    int g = blockIdx.x;
    int t = threadIdx.x;  // 128
    __shared__ float gv[128];
    __shared__ float hid[128];
    float inv = 1.0f / fmaxf(cnt[g], 1.0f);
    gv[t] = gsum[(size_t)g * DIM + t] * inv;
    __syncthreads();
    float acc = bc1[t];
    for (int k = 0; k < 128; k++) acc += gv[k] * Wc1[k * 128 + t];
    hid[t] = fmaxf(acc, 0.f);
    __syncthreads();
    if (t < 4) {
        float o = bc2[t];
        for (int k = 0; k < 128; k++) o += hid[k] * Wc2[k * 4 + t];
        out[g * 4 + t] = o;
    }
}

// ================= launch =================

extern "C" void kernel_launch(void* const* d_in, const int* in_sizes, int n_in,
                              void* d_out, int out_size, void* d_ws, size_t ws_size,
                              hipStream_t stream) {
    const float* x     = (const float*)d_in[0];
    const int*   ei    = (const int*)d_in[1];  // [2, E]: src then dst
    const float* attr  = (const float*)d_in[2];
    // d_in[3] edge_weight: unused by reference
    const int*   batch = (const int*)d_in[4];
    const float* W0  = (const float*)d_in[5];
    const float* b0  = (const float*)d_in[6];
    const float* W1  = (const float*)d_in[7];
    const float* b1  = (const float*)d_in[8];
    const float* Wc1 = (const float*)d_in[9];
    const float* bc1 = (const float*)d_in[10];
    const float* Wc2 = (const float*)d_in[11];
    const float* bc2 = (const float*)d_in[12];
    float* out = (float*)d_out;

    char* ws = (char*)d_ws;
    __half*             bufH16 = (__half*)(ws + 0);                  // 12,800,000
    __half*             bufA16 = (__half*)(ws + 12800000);           // 12,800,000
    unsigned int*       epack  = (unsigned int*)(ws + 25600000);     // 12,800,000
    unsigned long long* packed = (unsigned long long*)(ws + 38400000);  // 400,000
    float*              gsum   = (float*)(ws + 38800000);            //     65,536
    float*              cnt    = (float*)(ws + 38865536);            //        512
    _Float16*           Wt0    = (_Float16*)(ws + 38866048);         //     32,768
    _Float16*           Wt1    = (_Float16*)(ws + 38898816);         //     32,768

    const int* src = ei;
    const int* dst = ei + N_EDGES;

    const int NB_C = (N_EDGES + 255) / 256;            // 3125 chunks
    const int NB_G = ((N_NODES + 31) / 32) * 4;        // 1563 node-blocks x 4 cg
    const int NB_M = (N_NODES + 63) / 64;              // 782

    // zero packed+gsum+cnt (contiguous 466,048 B) without a kernel launch
    (void)hipMemsetAsync(ws + 38400000, 0, 466048, stream);

    // XCD-sliced one-pass CSR build + W transpose
    k_build<<<NB_C * 8 + 128, 256, 0, stream>>>(src, dst, attr, W0, W1, packed,
                                                epack, Wt0, Wt1, N_EDGES, NB_C);

    // layer 1: MFMA gemm (H' = dinv*(x@W0), fp16) + column-sliced gather
    k_gemm_mfma<float><<<NB_M, 256, 0, stream>>>(x, Wt0, packed, bufH16, N_NODES);
    k_gather<false><<<NB_G, 256, 0, stream>>>(bufH16, packed, epack, b0,
                                              batch, bufA16, gsum, cnt, N_NODES);

    // layer 2: MFMA gemm (fp16 A) + column-sliced gather w/ segmented pool
    k_gemm_mfma<_Float16><<<NB_M, 256, 0, stream>>>((const _Float16*)bufA16, Wt1,
                                                    packed, bufH16, N_NODES);
    k_gather<true><<<NB_G, 256, 0, stream>>>(bufH16, packed, epack, b1,
                                             batch, nullptr, gsum, cnt, N_NODES);

    // classifier
    k_classifier<<<NUM_GRAPHS, 128, 0, stream>>>(gsum, cnt, Wc1, bc1, Wc2, bc2, out);
}